// Round 2
// baseline (14824.979 us; speedup 1.0000x reference)
//
#include <hip/hip_runtime.h>
#include <hip/hip_bf16.h>
#include <hip/hip_fp16.h>

// Problem constants
#define B_ 64
#define T_ 512
#define D_ 256
#define H_ 512
// rows of the big GEMMs
#define M_ (B_*T_)          // 32768

typedef __attribute__((ext_vector_type(8))) short bf16x8;
typedef __attribute__((ext_vector_type(4))) float f32x4;
typedef _Float16 half_t;
typedef __attribute__((ext_vector_type(2))) _Float16 half2_t;

__device__ __forceinline__ unsigned short f32_to_bf16(float f) {
    unsigned u = __builtin_bit_cast(unsigned, f);
    unsigned r = (u + 0x7fffu + ((u >> 16) & 1u)) >> 16;
    return (unsigned short)r;
}
__device__ __forceinline__ float bf16_to_f32(unsigned short h) {
    unsigned u = ((unsigned)h) << 16;
    return __builtin_bit_cast(float, u);
}
__device__ __forceinline__ unsigned pkh2(float a, float b) {
    half2_t h; h.x = (half_t)a; h.y = (half_t)b;
    return __builtin_bit_cast(unsigned, h);
}
__device__ __forceinline__ half2_t uph2(unsigned u) {
    return __builtin_bit_cast(half2_t, u);
}

#if __has_builtin(__builtin_amdgcn_fdot2)
__device__ __forceinline__ float fdot2(half2_t a, half2_t b, float c) {
    return __builtin_amdgcn_fdot2(a, b, c, false);
}
#else
__device__ __forceinline__ float fdot2(half2_t a, half2_t b, float c) {
    return c + (float)a.x * (float)b.x + (float)a.y * (float)b.y;
}
#endif

// ---------------------------------------------------------------------------
// Build transposed/concatenated bf16 weights for the two big MFMA GEMMs.
//  WcatT bf16 [2048][256]:  n<512: We2h, <1024: Wr_x, <1536: Wz_x, else Wn_x
//  biascat f32 [2048]     :  {0, br, bz, bn}
//  WoT   bf16 [256][512]  :  transpose of Wo [512][256]
// ---------------------------------------------------------------------------
__global__ void build_wt(const float* __restrict__ We2h, const float* __restrict__ Wrx,
                         const float* __restrict__ Wzx, const float* __restrict__ Wnx,
                         const float* __restrict__ br, const float* __restrict__ bz,
                         const float* __restrict__ bn, const float* __restrict__ Wo,
                         unsigned short* __restrict__ WcatT, float* __restrict__ biascat,
                         unsigned short* __restrict__ WoT) {
    int tid = blockIdx.x * blockDim.x + threadIdx.x;
    const int total1 = 2048 * 256;
    if (tid < total1) {
        int n = tid >> 8, k = tid & 255;
        int sel = n >> 9, nl = n & 511;
        const float* W = sel == 0 ? We2h : sel == 1 ? Wrx : sel == 2 ? Wzx : Wnx;
        WcatT[tid] = f32_to_bf16(W[k * 512 + nl]);     // source W is [256][512]
        if (k == 0) {
            float bv = sel == 0 ? 0.f : sel == 1 ? br[nl] : sel == 2 ? bz[nl] : bn[nl];
            biascat[n] = bv;
        }
    } else {
        int t2 = tid - total1;
        if (t2 < 256 * 512) {
            int n = t2 >> 9, k = t2 & 511;
            WoT[t2] = f32_to_bf16(Wo[k * 256 + n]);    // Wo is [512][256]
        }
    }
}

// ---------------------------------------------------------------------------
// Build packed f16 recurrent weights for the scan.
//  Wrz uint4 [256][512]: (k4,j) -> {Wr[4k4..+1], Wr[4k4+2..+3], Wz.., Wz..}
//  where Wr_cat rows 0..511 = Wr_h, 512..1023 = Wr_e  (same for z / n)
//  Wn  uint2 [256][512]
// ---------------------------------------------------------------------------
__global__ void build_wscan(const float* __restrict__ Wrh, const float* __restrict__ Wre,
                            const float* __restrict__ Wzh, const float* __restrict__ Wze,
                            const float* __restrict__ Wnh, const float* __restrict__ Wne,
                            uint4* __restrict__ Wrz, uint2* __restrict__ Wn) {
    int tid = blockIdx.x * blockDim.x + threadIdx.x;
    if (tid >= 256 * 512) return;
    int k4 = tid >> 9, j = tid & 511;
    int k0 = 4 * k4;
    float rv[4], zv[4], nv[4];
#pragma unroll
    for (int e = 0; e < 4; e++) {
        int k = k0 + e;
        if (k < 512) {
            rv[e] = Wrh[k * 512 + j]; zv[e] = Wzh[k * 512 + j]; nv[e] = Wnh[k * 512 + j];
        } else {
            int kk = k - 512;
            rv[e] = Wre[kk * 512 + j]; zv[e] = Wze[kk * 512 + j]; nv[e] = Wne[kk * 512 + j];
        }
    }
    Wrz[tid] = make_uint4(pkh2(rv[0], rv[1]), pkh2(rv[2], rv[3]),
                          pkh2(zv[0], zv[1]), pkh2(zv[2], zv[3]));
    Wn[tid]  = make_uint2(pkh2(nv[0], nv[1]), pkh2(nv[2], nv[3]));
}

// ---------------------------------------------------------------------------
// bf16 MFMA GEMM, 128x128 tile, BK=64, 4 waves (2x2), 4x4 16x16x32 frags/wave.
//  A: fp32 [M][K] (converted to bf16 during staging)
//  BT: bf16 [N][K]  (B transposed: row n holds column n's K elements)
//  C: bf16 [M][N] (OUT_BF16=1) or fp32 (OUT_BF16=0); bias[N] added.
// ---------------------------------------------------------------------------
template <int OUT_BF16>
__global__ __launch_bounds__(256)
void gemm_bf16_kernel(const float* __restrict__ A, const unsigned short* __restrict__ BT,
                      const float* __restrict__ bias, void* __restrict__ C,
                      int M, int N, int K) {
    __shared__ unsigned short Asm[128 * 64];
    __shared__ unsigned short Bsm[128 * 64];
    const int tid = threadIdx.x;
    const int bm = blockIdx.x, bn = blockIdx.y;
    const int lane = tid & 63, wid = tid >> 6;
    const int wm = wid >> 1, wn = wid & 1;
    const int lr = lane & 15, lg = lane >> 4;

    f32x4 acc[4][4] = {};

    const int srow = tid >> 1, shalf = tid & 1;      // staging: 128 rows x 2 k-halves
    const float* Arow = A + (size_t)(bm * 128 + srow) * K + shalf * 32;
    const unsigned short* Brow = BT + (size_t)(bn * 128 + srow) * K + shalf * 32;
    unsigned short* As = &Asm[srow * 64 + shalf * 32];
    unsigned short* Bs = &Bsm[srow * 64 + shalf * 32];

    for (int kt = 0; kt < K; kt += 64) {
        // stage A: fp32 -> bf16 (32 floats -> 32 shorts per thread)
#pragma unroll
        for (int q = 0; q < 8; q++) {
            float4 v = *(const float4*)(Arow + kt + q * 4);
            unsigned p0 = ((unsigned)f32_to_bf16(v.y) << 16) | f32_to_bf16(v.x);
            unsigned p1 = ((unsigned)f32_to_bf16(v.w) << 16) | f32_to_bf16(v.z);
            *(uint2*)(As + q * 4) = make_uint2(p0, p1);
        }
        // stage B: copy 32 bf16 = 4 x uint4 (uint4 covers 8 shorts)
#pragma unroll
        for (int q = 0; q < 4; q++) {
            uint4 v = *(const uint4*)(Brow + kt + q * 8);
            *(uint4*)(Bs + q * 8) = v;
        }
        __syncthreads();
#pragma unroll
        for (int ks = 0; ks < 2; ks++) {
            bf16x8 af[4], bfr[4];
#pragma unroll
            for (int m = 0; m < 4; m++)
                af[m] = *(const bf16x8*)&Asm[(wm * 64 + m * 16 + lr) * 64 + ks * 32 + lg * 8];
#pragma unroll
            for (int n2 = 0; n2 < 4; n2++)
                bfr[n2] = *(const bf16x8*)&Bsm[(wn * 64 + n2 * 16 + lr) * 64 + ks * 32 + lg * 8];
#pragma unroll
            for (int m = 0; m < 4; m++)
#pragma unroll
                for (int n2 = 0; n2 < 4; n2++)
                    acc[m][n2] = __builtin_amdgcn_mfma_f32_16x16x32_bf16(
                        af[m], bfr[n2], acc[m][n2], 0, 0, 0);
        }
        __syncthreads();
    }
    // epilogue: D[row = lg*4+i][col = lr] per fragment (verified m89/m91 mapping)
#pragma unroll
    for (int m = 0; m < 4; m++) {
        int row0 = bm * 128 + wm * 64 + m * 16 + lg * 4;
#pragma unroll
        for (int n2 = 0; n2 < 4; n2++) {
            int col = bn * 128 + wn * 64 + n2 * 16 + lr;
            float bv = bias[col];
#pragma unroll
            for (int i = 0; i < 4; i++) {
                float val = acc[m][n2][i] + bv;
                size_t idx = (size_t)(row0 + i) * N + col;
                if (OUT_BF16) ((unsigned short*)C)[idx] = f32_to_bf16(val);
                else          ((float*)C)[idx] = val;
            }
        }
    }
}

// ---------------------------------------------------------------------------
// Recurrent scan. 64 blocks (one per batch element) x 512 threads (one per
// hidden column). State fp32 in LDS; matvec operands packed f16; weights
// streamed from L2 each step (f16, ~3 MB/step/block).
// ---------------------------------------------------------------------------
__global__ __launch_bounds__(512)
void scan_kernel(const unsigned short* __restrict__ xproj, // [M_][2048] bf16: e|r|z|n
                 const float* __restrict__ h0,             // [B_][512]
                 const uint4* __restrict__ Wrz,            // [256][512]
                 const uint2* __restrict__ Wn,             // [256][512]
                 float* __restrict__ out_hseq)             // [M_][512] fp32
{
    __shared__ float h_s[512], e_s[512], rh_s[512], re_s[512];
    __shared__ unsigned he_pk[512];   // half2-packed [h(512); e(512)]
    __shared__ unsigned rr_pk[512];   // half2-packed [r*h(512); r*e(512)]

    const int b = blockIdx.x, j = threadIdx.x;
    h_s[j] = h0[b * 512 + j];
    __syncthreads();

    for (int t = 0; t < T_; t++) {
        const unsigned short* row = xproj + (size_t)(b * T_ + t) * 2048;
        float xe = bf16_to_f32(row[j]);
        float xr = bf16_to_f32(row[512 + j]);
        float xz = bf16_to_f32(row[1024 + j]);
        float xn = bf16_to_f32(row[1536 + j]);
        float hj = h_s[j];
        float ej = xe - hj;
        e_s[j] = ej;
        __syncthreads();
        // pack [h;e] into half2 words
        {
            float a, bv;
            if (j < 256) { a = h_s[2 * j];       bv = h_s[2 * j + 1]; }
            else         { a = e_s[2 * j - 512]; bv = e_s[2 * j - 511]; }
            he_pk[j] = pkh2(a, bv);
        }
        __syncthreads();
        // phase A: r,z pre-activations (contraction over 1024 = [h;e])
        float accr = xr, accz = xz;
        const uint4* wp = Wrz + j;
#pragma unroll 4
        for (int k4 = 0; k4 < 256; k4++) {
            uint2 he2 = *(const uint2*)&he_pk[2 * k4];
            uint4 w = *wp; wp += 512;
            half2_t v01 = uph2(he2.x), v23 = uph2(he2.y);
            accr = fdot2(v01, uph2(w.x), accr);
            accr = fdot2(v23, uph2(w.y), accr);
            accz = fdot2(v01, uph2(w.z), accz);
            accz = fdot2(v23, uph2(w.w), accz);
        }
        float r = 1.f / (1.f + expf(-accr));
        float z = 1.f / (1.f + expf(-accz));
        rh_s[j] = r * hj;
        re_s[j] = r * ej;
        __syncthreads();
        {
            float a, bv;
            if (j < 256) { a = rh_s[2 * j];       bv = rh_s[2 * j + 1]; }
            else         { a = re_s[2 * j - 512]; bv = re_s[2 * j - 511]; }
            rr_pk[j] = pkh2(a, bv);
        }
        __syncthreads();
        // phase B: n pre-activation (contraction over 1024 = [r*h; r*e])
        float accn = xn;
        const uint2* wnp = Wn + j;
#pragma unroll 4
        for (int k4 = 0; k4 < 256; k4++) {
            uint2 p2 = *(const uint2*)&rr_pk[2 * k4];
            uint2 w = *wnp; wnp += 512;
            accn = fdot2(uph2(p2.x), uph2(w.x), accn);
            accn = fdot2(uph2(p2.y), uph2(w.y), accn);
        }
        float n = tanhf(accn);
        float hnew = (1.f - z) * hj + z * n;
        __syncthreads();
        h_s[j] = hnew;
        out_hseq[(size_t)(b * T_ + t) * 512 + j] = hnew;
    }
}

// ---------------------------------------------------------------------------
extern "C" void kernel_launch(void* const* d_in, const int* in_sizes, int n_in,
                              void* d_out, int out_size, void* d_ws, size_t ws_size,
                              hipStream_t stream) {
    const float* x    = (const float*)d_in[0];
    const float* h0   = (const float*)d_in[1];
    const float* We2h = (const float*)d_in[2];
    const float* Wrx  = (const float*)d_in[3];
    const float* Wrh  = (const float*)d_in[4];
    const float* Wre  = (const float*)d_in[5];
    const float* br   = (const float*)d_in[6];
    const float* Wzx  = (const float*)d_in[7];
    const float* Wzh  = (const float*)d_in[8];
    const float* Wze  = (const float*)d_in[9];
    const float* bz   = (const float*)d_in[10];
    const float* Wnx  = (const float*)d_in[11];
    const float* Wnh  = (const float*)d_in[12];
    const float* Wne  = (const float*)d_in[13];
    const float* bn   = (const float*)d_in[14];
    const float* Wo   = (const float*)d_in[15];
    const float* bo   = (const float*)d_in[16];

    // workspace layout (bytes)
    char* w = (char*)d_ws;
    unsigned short* xproj = (unsigned short*)(w);                  // 32768*2048*2 = 134217728
    unsigned short* WcatT = (unsigned short*)(w + 134217728);      // 1048576
    unsigned short* WoT   = (unsigned short*)(w + 135266304);      // 262144
    uint4*          Wrz   = (uint4*)(w + 135528448);               // 2097152
    uint2*          Wn    = (uint2*)(w + 137625600);               // 1048576
    float*          biascat = (float*)(w + 138674176);             // 8192

    float* out   = (float*)d_out;                 // [B,T,D]
    float* hseq  = (float*)d_out + (size_t)M_ * D_; // [B,T,H]

    // 1. build weights
    {
        int total = 2048 * 256 + 256 * 512;
        build_wt<<<(total + 255) / 256, 256, 0, stream>>>(
            We2h, Wrx, Wzx, Wnx, br, bz, bn, Wo, WcatT, biascat, WoT);
        build_wscan<<<(256 * 512 + 255) / 256, 256, 0, stream>>>(
            Wrh, Wre, Wzh, Wze, Wnh, Wne, Wrz, Wn);
    }
    // 2. pre-projections: [32768,256] @ [256,2048] -> bf16 xproj (+bias)
    {
        dim3 grid(M_ / 128, 2048 / 128);
        gemm_bf16_kernel<1><<<grid, 256, 0, stream>>>(x, WcatT, biascat, xproj,
                                                      M_, 2048, D_);
    }
    // 3. recurrent scan -> hseq (fp32, into d_out)
    scan_kernel<<<B_, 512, 0, stream>>>(xproj, h0, Wrz, Wn, hseq);
    // 4. readout: [32768,512] @ [512,256] + bo -> out (fp32)
    {
        dim3 grid(M_ / 128, D_ / 128);
        gemm_bf16_kernel<0><<<grid, 256, 0, stream>>>(hseq, WoT, bo, out,
                                                      M_, D_, H_);
    }
}

// Round 4
// 11898.973 us; speedup vs baseline: 1.2459x; 1.2459x over previous
//
#include <hip/hip_runtime.h>
#include <hip/hip_bf16.h>
#include <hip/hip_fp16.h>

// Problem constants
#define B_ 64
#define T_ 512
#define D_ 256
#define H_ 512
#define M_ (B_*T_)          // 32768

#define NBLK 128            // scan blocks
#define JO 4                // hidden columns owned per scan block

typedef unsigned int uint;
typedef __attribute__((ext_vector_type(8))) short bf16x8;
typedef __attribute__((ext_vector_type(4))) float f32x4;
typedef _Float16 half_t;
typedef __attribute__((ext_vector_type(2))) _Float16 half2_t;

__device__ __forceinline__ unsigned short f32_to_bf16(float f) {
    unsigned u = __builtin_bit_cast(unsigned, f);
    unsigned r = (u + 0x7fffu + ((u >> 16) & 1u)) >> 16;
    return (unsigned short)r;
}
__device__ __forceinline__ float bf16_to_f32(unsigned short h) {
    unsigned u = ((unsigned)h) << 16;
    return __builtin_bit_cast(float, u);
}
__device__ __forceinline__ unsigned pkh2(float a, float b) {
    half2_t h; h.x = (half_t)a; h.y = (half_t)b;
    return __builtin_bit_cast(unsigned, h);
}
__device__ __forceinline__ half2_t uph2(unsigned u) {
    return __builtin_bit_cast(half2_t, u);
}

#if __has_builtin(__builtin_amdgcn_fdot2)
__device__ __forceinline__ float fdot2(half2_t a, half2_t b, float c) {
    return __builtin_amdgcn_fdot2(a, b, c, false);
}
#else
__device__ __forceinline__ float fdot2(half2_t a, half2_t b, float c) {
    return c + (float)a.x * (float)b.x + (float)a.y * (float)b.y;
}
#endif

// agent-scope (device, cross-XCD coherent) atomics for scan traffic
__device__ __forceinline__ uint ald(const uint* p) {
    return __hip_atomic_load(p, __ATOMIC_RELAXED, __HIP_MEMORY_SCOPE_AGENT);
}
__device__ __forceinline__ void ast(uint* p, uint v) {
    __hip_atomic_store(p, v, __ATOMIC_RELAXED, __HIP_MEMORY_SCOPE_AGENT);
}
__device__ __forceinline__ void ast_rel(uint* p, uint v) {
    __hip_atomic_store(p, v, __ATOMIC_RELEASE, __HIP_MEMORY_SCOPE_AGENT);
}
__device__ __forceinline__ uint ald_acq(const uint* p) {
    return __hip_atomic_load(p, __ATOMIC_ACQUIRE, __HIP_MEMORY_SCOPE_AGENT);
}

__device__ __forceinline__ float sigmoidf_(float x) {
    return 1.f / (1.f + __expf(-x));
}

// ---------------------------------------------------------------------------
// P = We2h @ W  for r and z gates:  P_r[k][j] = sum_kk We2h[k][kk]*Wre[kk][j]
// ---------------------------------------------------------------------------
__global__ void comp_p(const float* __restrict__ We2h, const float* __restrict__ Wre,
                       const float* __restrict__ Wze,
                       float* __restrict__ Pr, float* __restrict__ Pz) {
    int tid = blockIdx.x * blockDim.x + threadIdx.x;   // 256*512
    if (tid >= 256 * 512) return;
    int k = tid >> 9, j = tid & 511;
    float ar = 0.f, az = 0.f;
    for (int kk = 0; kk < 512; kk++) {
        float e = We2h[k * 512 + kk];
        ar += e * Wre[kk * 512 + j];
        az += e * Wze[kk * 512 + j];
    }
    Pr[tid] = ar;
    Pz[tid] = az;
}

// ---------------------------------------------------------------------------
// Build bf16 weights for the big GEMMs.
//  WcatT bf16 [2048 n][256 k]: n<512: We2h; <1024: Wrx+Pr; <1536: Wzx+Pz; else Wnx
//  biascat f32 [2048] = {0, br, bz, bn};  WoT bf16 [256][512] = Wo^T
// ---------------------------------------------------------------------------
__global__ void build_wt(const float* __restrict__ We2h, const float* __restrict__ Wrx,
                         const float* __restrict__ Wzx, const float* __restrict__ Wnx,
                         const float* __restrict__ Pr, const float* __restrict__ Pz,
                         const float* __restrict__ br, const float* __restrict__ bz,
                         const float* __restrict__ bn, const float* __restrict__ Wo,
                         unsigned short* __restrict__ WcatT, float* __restrict__ biascat,
                         unsigned short* __restrict__ WoT) {
    int tid = blockIdx.x * blockDim.x + threadIdx.x;
    const int total1 = 2048 * 256;
    if (tid < total1) {
        int n = tid >> 8, k = tid & 255;
        int sel = n >> 9, nl = n & 511;
        float v;
        if (sel == 0)      v = We2h[k * 512 + nl];
        else if (sel == 1) v = Wrx[k * 512 + nl] + Pr[k * 512 + nl];
        else if (sel == 2) v = Wzx[k * 512 + nl] + Pz[k * 512 + nl];
        else               v = Wnx[k * 512 + nl];
        WcatT[tid] = f32_to_bf16(v);
        if (k == 0) {
            float bv = sel == 0 ? 0.f : sel == 1 ? br[nl] : sel == 2 ? bz[nl] : bn[nl];
            biascat[n] = bv;
        }
    } else {
        int t2 = tid - total1;
        if (t2 < 256 * 512) {
            int n = t2 >> 9, k = t2 & 511;
            WoT[t2] = f32_to_bf16(Wo[k * 256 + n]);
        }
    }
}

// ---------------------------------------------------------------------------
// Packed f16 recurrent weights (transformed):
//  warz uint2 [256 kp][512 j]: {pkh2(Ar[2kp][j],Ar[2kp+1][j]), pkh2(Az..)},
//      Ar = Wrh - Wre, Az = Wzh - Wze
//  wan  uint  [512 k][512 j]:  pkh2(An[k][j], Wne[k][j]),  An = Wnh - Wne
// ---------------------------------------------------------------------------
__global__ void build_wscan(const float* __restrict__ Wrh, const float* __restrict__ Wre,
                            const float* __restrict__ Wzh, const float* __restrict__ Wze,
                            const float* __restrict__ Wnh, const float* __restrict__ Wne,
                            uint2* __restrict__ warz, uint* __restrict__ wan) {
    int tid = blockIdx.x * blockDim.x + threadIdx.x;
    if (tid < 256 * 512) {
        int kp = tid >> 9, j = tid & 511;
        int k0 = 2 * kp;
        float ar0 = Wrh[k0 * 512 + j] - Wre[k0 * 512 + j];
        float ar1 = Wrh[(k0 + 1) * 512 + j] - Wre[(k0 + 1) * 512 + j];
        float az0 = Wzh[k0 * 512 + j] - Wze[k0 * 512 + j];
        float az1 = Wzh[(k0 + 1) * 512 + j] - Wze[(k0 + 1) * 512 + j];
        warz[tid] = make_uint2(pkh2(ar0, ar1), pkh2(az0, az1));
    }
    int t2 = tid - 256 * 512;
    if (t2 >= 0 && t2 < 512 * 512) {
        int k = t2 >> 9, j = t2 & 511;
        float an = Wnh[k * 512 + j] - Wne[k * 512 + j];
        wan[t2] = pkh2(an, Wne[k * 512 + j]);
    }
}

// ---------------------------------------------------------------------------
// init hbuf: [256 kp][64 m] uint = (f16 h[m][2kp], f16 h[m][2kp+1])
// ---------------------------------------------------------------------------
__global__ void init_hbuf(const float* __restrict__ h0, uint* __restrict__ hbuf) {
    int tid = blockIdx.x * blockDim.x + threadIdx.x;   // 256*64
    if (tid >= 256 * 64) return;
    int kp = tid >> 6, m = tid & 63;
    hbuf[tid] = pkh2(h0[m * 512 + 2 * kp], h0[m * 512 + 2 * kp + 1]);
}

// ---------------------------------------------------------------------------
// GEMM-X: A fp32 [M][256] (rows indexed (b,t)), BT bf16 [2048][256].
// Block tile: 2 time-steps x all 64 batches (128 rows) x 128 cols.
// Output written DIRECTLY to xT[t][col][m] bf16 (scan-friendly layout).
// ---------------------------------------------------------------------------
__global__ __launch_bounds__(256)
void gemmx_kernel(const float* __restrict__ A, const unsigned short* __restrict__ BT,
                  const float* __restrict__ bias, unsigned short* __restrict__ xT) {
    __shared__ unsigned short Asm[128 * 64];
    __shared__ unsigned short Bsm[128 * 64];
    __shared__ unsigned short Csm[128][128];   // [col][row]
    const int tid = threadIdx.x;
    const int t0 = blockIdx.x * 2;        // time-pair
    const int c0 = blockIdx.y * 128;      // col tile
    const int lane = tid & 63, wid = tid >> 6;
    const int wm = wid >> 1, wn = wid & 1;
    const int lr = lane & 15, lg = lane >> 4;

    f32x4 acc[4][4] = {};

    const int srow = tid >> 1, shalf = tid & 1;
    const int rowA = (srow & 63) * 512 + t0 + (srow >> 6);     // (b,t) -> A row
    const float* Arow = A + (size_t)rowA * 256 + shalf * 32;
    const unsigned short* Brow = BT + (size_t)(c0 + srow) * 256 + shalf * 32;
    unsigned short* As = &Asm[srow * 64 + shalf * 32];
    unsigned short* Bs = &Bsm[srow * 64 + shalf * 32];

    for (int kt = 0; kt < 256; kt += 64) {
#pragma unroll
        for (int q = 0; q < 8; q++) {
            float4 v = *(const float4*)(Arow + kt + q * 4);
            unsigned p0 = ((unsigned)f32_to_bf16(v.y) << 16) | f32_to_bf16(v.x);
            unsigned p1 = ((unsigned)f32_to_bf16(v.w) << 16) | f32_to_bf16(v.z);
            *(uint2*)(As + q * 4) = make_uint2(p0, p1);
        }
#pragma unroll
        for (int q = 0; q < 4; q++) {
            uint4 v = *(const uint4*)(Brow + kt + q * 8);
            *(uint4*)(Bs + q * 8) = v;
        }
        __syncthreads();
#pragma unroll
        for (int ks = 0; ks < 2; ks++) {
            bf16x8 af[4], bfr[4];
#pragma unroll
            for (int m = 0; m < 4; m++)
                af[m] = *(const bf16x8*)&Asm[(wm * 64 + m * 16 + lr) * 64 + ks * 32 + lg * 8];
#pragma unroll
            for (int n2 = 0; n2 < 4; n2++)
                bfr[n2] = *(const bf16x8*)&Bsm[(wn * 64 + n2 * 16 + lr) * 64 + ks * 32 + lg * 8];
#pragma unroll
            for (int m = 0; m < 4; m++)
#pragma unroll
                for (int n2 = 0; n2 < 4; n2++)
                    acc[m][n2] = __builtin_amdgcn_mfma_f32_16x16x32_bf16(
                        af[m], bfr[n2], acc[m][n2], 0, 0, 0);
        }
        __syncthreads();
    }
    // stage to Csm[col][row] with bias
#pragma unroll
    for (int m = 0; m < 4; m++) {
        int r0 = wm * 64 + m * 16 + lg * 4;
#pragma unroll
        for (int n2 = 0; n2 < 4; n2++) {
            int c = wn * 64 + n2 * 16 + lr;
            float bv = bias[c0 + c];
#pragma unroll
            for (int i = 0; i < 4; i++)
                Csm[c][r0 + i] = f32_to_bf16(acc[m][n2][i] + bv);
        }
    }
    __syncthreads();
    // write xT[t][c0+c][b]: contiguous [128 c][64 b] region per t
#pragma unroll
    for (int th = 0; th < 2; th++) {
        uint4* dst = (uint4*)(xT + ((size_t)(t0 + th) * 2048 + c0) * 64);
        for (int q = tid; q < 1024; q += 256) {        // 8192 elems / 8
            int c = q >> 3, b0 = (q & 7) * 8;
            dst[q] = *(const uint4*)&Csm[c][th * 64 + b0];
        }
        __syncthreads();
    }
}

// ---------------------------------------------------------------------------
// Readout GEMM: A fp32 [M][K], BT bf16 [N][K], C fp32 + bias.
// ---------------------------------------------------------------------------
__global__ __launch_bounds__(256)
void gemm_out_kernel(const float* __restrict__ A, const unsigned short* __restrict__ BT,
                     const float* __restrict__ bias, float* __restrict__ C,
                     int M, int N, int K) {
    __shared__ unsigned short Asm[128 * 64];
    __shared__ unsigned short Bsm[128 * 64];
    const int tid = threadIdx.x;
    const int bm = blockIdx.x, bn = blockIdx.y;
    const int lane = tid & 63, wid = tid >> 6;
    const int wm = wid >> 1, wn = wid & 1;
    const int lr = lane & 15, lg = lane >> 4;

    f32x4 acc[4][4] = {};

    const int srow = tid >> 1, shalf = tid & 1;
    const float* Arow = A + (size_t)(bm * 128 + srow) * K + shalf * 32;
    const unsigned short* Brow = BT + (size_t)(bn * 128 + srow) * K + shalf * 32;
    unsigned short* As = &Asm[srow * 64 + shalf * 32];
    unsigned short* Bs = &Bsm[srow * 64 + shalf * 32];

    for (int kt = 0; kt < K; kt += 64) {
#pragma unroll
        for (int q = 0; q < 8; q++) {
            float4 v = *(const float4*)(Arow + kt + q * 4);
            unsigned p0 = ((unsigned)f32_to_bf16(v.y) << 16) | f32_to_bf16(v.x);
            unsigned p1 = ((unsigned)f32_to_bf16(v.w) << 16) | f32_to_bf16(v.z);
            *(uint2*)(As + q * 4) = make_uint2(p0, p1);
        }
#pragma unroll
        for (int q = 0; q < 4; q++) {
            uint4 v = *(const uint4*)(Brow + kt + q * 8);
            *(uint4*)(Bs + q * 8) = v;
        }
        __syncthreads();
#pragma unroll
        for (int ks = 0; ks < 2; ks++) {
            bf16x8 af[4], bfr[4];
#pragma unroll
            for (int m = 0; m < 4; m++)
                af[m] = *(const bf16x8*)&Asm[(wm * 64 + m * 16 + lr) * 64 + ks * 32 + lg * 8];
#pragma unroll
            for (int n2 = 0; n2 < 4; n2++)
                bfr[n2] = *(const bf16x8*)&Bsm[(wn * 64 + n2 * 16 + lr) * 64 + ks * 32 + lg * 8];
#pragma unroll
            for (int m = 0; m < 4; m++)
#pragma unroll
                for (int n2 = 0; n2 < 4; n2++)
                    acc[m][n2] = __builtin_amdgcn_mfma_f32_16x16x32_bf16(
                        af[m], bfr[n2], acc[m][n2], 0, 0, 0);
        }
        __syncthreads();
    }
#pragma unroll
    for (int m = 0; m < 4; m++) {
        int row0 = bm * 128 + wm * 64 + m * 16 + lg * 4;
#pragma unroll
        for (int n2 = 0; n2 < 4; n2++) {
            int col = bn * 128 + wn * 64 + n2 * 16 + lr;
            float bv = bias[col];
#pragma unroll
            for (int i = 0; i < 4; i++)
                C[(size_t)(row0 + i) * N + col] = acc[m][n2][i] + bv;
        }
    }
}

// ---------------------------------------------------------------------------
// Grid-synced weight-stationary scan.
// 128 blocks x 512 threads. Block bid owns j = bid*4 .. +4 (of 512 hidden).
// Per step: phase A computes r,z for owned j (dot over full h via hbuf),
// publishes (r*h, r*xe) pairs; phase B computes n + h-update, publishes h f16.
// Cross-block data via agent-scope atomics; flags use release/acquire.
// ---------------------------------------------------------------------------
__global__ __launch_bounds__(512)
void scan_sync(const unsigned short* __restrict__ xT,   // [512 t][2048 col][64 m] bf16
               const float* __restrict__ h0,            // [64 m][512 j]
               const uint2* __restrict__ warz,          // [256 kp][512 j]
               const uint* __restrict__ wan,            // [512 k][512 j]
               uint* __restrict__ hbuf,                 // [256 kp][64 m]
               uint* __restrict__ rhrxe,                // [512 k][64 m]
               uint* __restrict__ flags,                // [NBLK]
               float* __restrict__ hseq)                // [64 m][512 t][512 j] f32
{
    __shared__ uint2 Wrz_l[256][JO];                    // 8 KB
    __shared__ uint  Wn_l[512][JO];                     // 8 KB
    __shared__ float part[3][8][JO][64];                // 24 KB: 0=pr 1=pz 2=pn
    __shared__ float h_loc[JO][64], z_loc[JO][64];      // 2 KB

    const int bid = blockIdx.x, tid = threadIdx.x;
    const int lane = tid & 63, wv = tid >> 6;           // 8 waves
    const int j0 = bid * JO;

    // one-time: weights -> LDS, local h slice
    for (int i = tid; i < 256 * JO; i += 512) {
        int kp = i >> 2, j = i & 3;
        Wrz_l[kp][j] = warz[kp * 512 + j0 + j];
    }
    for (int i = tid; i < 512 * JO; i += 512) {
        int k = i >> 2, j = i & 3;
        Wn_l[k][j] = wan[k * 512 + j0 + j];
    }
    if (tid < JO * 64) {
        int j = tid & 3, m = tid >> 2;
        h_loc[j][m] = h0[m * 512 + j0 + j];
    }
    __syncthreads();

    for (int t = 0; t < T_; t++) {
        // ---- wait: all blocks finished phase B of step t-1 ----
        if (tid < NBLK) {
            uint target = 2u * t;
            int bspin = 1 << 22;
            while (ald_acq(&flags[tid]) < target) {
                if (--bspin < 0) break;
                __builtin_amdgcn_s_sleep(2);
            }
        }
        __syncthreads();

        // ---- phase A: r,z partial dots (wave wv covers kp = wv*32..+32) ----
        {
            uint hv[32];
#pragma unroll
            for (int q = 0; q < 32; q++)
                hv[q] = ald(&hbuf[(wv * 32 + q) * 64 + lane]);
            float ar[JO] = {0.f, 0.f, 0.f, 0.f}, az[JO] = {0.f, 0.f, 0.f, 0.f};
#pragma unroll
            for (int q = 0; q < 32; q++) {
                half2_t h2 = uph2(hv[q]);
#pragma unroll
                for (int j = 0; j < JO; j++) {
                    uint2 w = *(const uint2*)&Wrz_l[wv * 32 + q][j];
                    ar[j] = fdot2(h2, uph2(w.x), ar[j]);
                    az[j] = fdot2(h2, uph2(w.y), az[j]);
                }
            }
#pragma unroll
            for (int j = 0; j < JO; j++) {
                part[0][wv][j][lane] = ar[j];
                part[1][wv][j][lane] = az[j];
            }
        }
        __syncthreads();

        // ---- finalize A: sigmoid, publish (r*h, r*xe) ----
        if (tid < JO * 64) {
            int j = tid & 3, m = tid >> 2;
            int jg = j0 + j;
            float sr = 0.f, sz = 0.f;
#pragma unroll
            for (int w = 0; w < 8; w++) { sr += part[0][w][j][m]; sz += part[1][w][j][m]; }
            float xr = bf16_to_f32(xT[((size_t)t * 2048 + 512 + jg) * 64 + m]);
            float xz = bf16_to_f32(xT[((size_t)t * 2048 + 1024 + jg) * 64 + m]);
            float xe = bf16_to_f32(xT[((size_t)t * 2048 + jg) * 64 + m]);
            float r = sigmoidf_(xr + sr);
            float z = sigmoidf_(xz + sz);
            float h = h_loc[j][m];
            z_loc[j][m] = z;
            ast(&rhrxe[jg * 64 + m], pkh2(r * h, r * xe));
        }
        __syncthreads();                   // drains the rhrxe stores (vmcnt)
        if (tid == 0) ast_rel(&flags[bid], 2u * t + 1u);

        // ---- wait: all blocks published rhrxe for step t ----
        if (tid < NBLK) {
            uint target = 2u * t + 1u;
            int bspin = 1 << 22;
            while (ald_acq(&flags[tid]) < target) {
                if (--bspin < 0) break;
                __builtin_amdgcn_s_sleep(2);
            }
        }
        __syncthreads();

        // ---- phase B: n partial dots (wave wv covers k = wv*64..+64) ----
        {
            float an[JO] = {0.f, 0.f, 0.f, 0.f};
#pragma unroll
            for (int ch = 0; ch < 2; ch++) {
                uint rv[32];
#pragma unroll
                for (int q = 0; q < 32; q++)
                    rv[q] = ald(&rhrxe[(wv * 64 + ch * 32 + q) * 64 + lane]);
#pragma unroll
                for (int q = 0; q < 32; q++) {
                    half2_t p2 = uph2(rv[q]);
#pragma unroll
                    for (int j = 0; j < JO; j++)
                        an[j] = fdot2(p2, uph2(Wn_l[wv * 64 + ch * 32 + q][j]), an[j]);
                }
            }
#pragma unroll
            for (int j = 0; j < JO; j++) part[2][wv][j][lane] = an[j];
        }
        __syncthreads();

        // ---- finalize B: tanh, h update, write hseq ----
        if (tid < JO * 64) {
            int j = tid & 3, m = tid >> 2;
            int jg = j0 + j;
            float sn = 0.f;
#pragma unroll
            for (int w = 0; w < 8; w++) sn += part[2][w][j][m];
            float xn = bf16_to_f32(xT[((size_t)t * 2048 + 1536 + jg) * 64 + m]);
            float nn = tanhf(xn + sn);
            float z = z_loc[j][m];
            float h = h_loc[j][m];
            float hn = (1.f - z) * h + z * nn;
            h_loc[j][m] = hn;
            hseq[((size_t)m * 512 + t) * 512 + jg] = hn;   // plain store
        }
        __syncthreads();

        // ---- publish new h (f16 pairs) ----
        if (tid < (JO / 2) * 64) {
            int jp = tid & 1, m = tid >> 1;
            ast(&hbuf[(bid * 2 + jp) * 64 + m],
                pkh2(h_loc[2 * jp][m], h_loc[2 * jp + 1][m]));
        }
        __syncthreads();                   // drains hbuf stores
        if (tid == 0) ast_rel(&flags[bid], 2u * t + 2u);
    }
}

// ---------------------------------------------------------------------------
extern "C" void kernel_launch(void* const* d_in, const int* in_sizes, int n_in,
                              void* d_out, int out_size, void* d_ws, size_t ws_size,
                              hipStream_t stream) {
    const float* x    = (const float*)d_in[0];
    const float* h0   = (const float*)d_in[1];
    const float* We2h = (const float*)d_in[2];
    const float* Wrx  = (const float*)d_in[3];
    const float* Wrh  = (const float*)d_in[4];
    const float* Wre  = (const float*)d_in[5];
    const float* br   = (const float*)d_in[6];
    const float* Wzx  = (const float*)d_in[7];
    const float* Wzh  = (const float*)d_in[8];
    const float* Wze  = (const float*)d_in[9];
    const float* bz   = (const float*)d_in[10];
    const float* Wnx  = (const float*)d_in[11];
    const float* Wnh  = (const float*)d_in[12];
    const float* Wne  = (const float*)d_in[13];
    const float* bn   = (const float*)d_in[14];
    const float* Wo   = (const float*)d_in[15];
    const float* bo   = (const float*)d_in[16];

    // workspace layout (bytes)
    char* w = (char*)d_ws;
    unsigned short* xT    = (unsigned short*)(w);                  // 134217728
    uint2*          warz  = (uint2*)(w + 134217728);               // 1048576
    uint*           wan   = (uint*)(w + 135266304);                // 1048576
    unsigned short* WcatT = (unsigned short*)(w + 136314880);      // 1048576
    unsigned short* WoT   = (unsigned short*)(w + 137363456);      // 262144
    float*          biascat = (float*)(w + 137625600);             // 8192
    float*          Pr    = (float*)(w + 137633792);               // 524288
    float*          Pz    = (float*)(w + 138158080);               // 524288
    uint*           hbuf  = (uint*)(w + 138682368);                // 65536
    uint*           rhrxe = (uint*)(w + 138747904);                // 131072
    uint*           flags = (uint*)(w + 138878976);                // 512

    float* out  = (float*)d_out;                    // [B,T,D]
    float* hseq = (float*)d_out + (size_t)M_ * D_;  // [B,T,H]

    hipMemsetAsync(flags, 0, NBLK * sizeof(uint), stream);

    // 1. composite input weights + packed scan weights
    comp_p<<<(256 * 512 + 255) / 256, 256, 0, stream>>>(We2h, Wre, Wze, Pr, Pz);
    build_wt<<<(2048 * 256 + 256 * 512 + 255) / 256, 256, 0, stream>>>(
        We2h, Wrx, Wzx, Wnx, Pr, Pz, br, bz, bn, Wo, WcatT, biascat, WoT);
    build_wscan<<<(256 * 512 + 512 * 512 + 255) / 256, 256, 0, stream>>>(
        Wrh, Wre, Wzh, Wze, Wnh, Wne, warz, wan);
    init_hbuf<<<(256 * 64 + 255) / 256, 256, 0, stream>>>(h0, hbuf);

    // 2. pre-projections directly into xT[t][col][m]
    {
        dim3 grid(T_ / 2, 2048 / 128);
        gemmx_kernel<<<grid, 256, 0, stream>>>(x, WcatT, biascat, xT);
    }
    // 3. grid-synced scan -> hseq
    scan_sync<<<NBLK, 512, 0, stream>>>(xT, h0, warz, wan, hbuf, rhrxe, flags, hseq);
    // 4. readout: [32768,512] @ [512,256] + bo -> out
    {
        dim3 grid(M_ / 128, D_ / 128);
        gemm_out_kernel<<<grid, 256, 0, stream>>>(hseq, WoT, bo, out, M_, D_, H_);
    }
}

// Round 5
// 8092.392 us; speedup vs baseline: 1.8320x; 1.4704x over previous
//
#include <hip/hip_runtime.h>
#include <hip/hip_bf16.h>
#include <hip/hip_fp16.h>

// Problem constants
#define B_ 64
#define T_ 512
#define D_ 256
#define H_ 512
#define M_ (B_*T_)          // 32768

#define NBLK 64             // scan blocks
#define JO 8                // hidden columns owned per scan block

typedef unsigned int uint;
typedef __attribute__((ext_vector_type(8))) short bf16x8;
typedef __attribute__((ext_vector_type(4))) float f32x4;
typedef _Float16 half_t;
typedef __attribute__((ext_vector_type(2))) _Float16 half2_t;

__device__ __forceinline__ unsigned short f32_to_bf16(float f) {
    unsigned u = __builtin_bit_cast(unsigned, f);
    unsigned r = (u + 0x7fffu + ((u >> 16) & 1u)) >> 16;
    return (unsigned short)r;
}
__device__ __forceinline__ float bf16_to_f32(unsigned short h) {
    unsigned u = ((unsigned)h) << 16;
    return __builtin_bit_cast(float, u);
}
__device__ __forceinline__ unsigned pkh2(float a, float b) {
    half2_t h; h.x = (half_t)a; h.y = (half_t)b;
    return __builtin_bit_cast(unsigned, h);
}
__device__ __forceinline__ half2_t uph2(unsigned u) {
    return __builtin_bit_cast(half2_t, u);
}

#if __has_builtin(__builtin_amdgcn_fdot2)
__device__ __forceinline__ float fdot2(half2_t a, half2_t b, float c) {
    return __builtin_amdgcn_fdot2(a, b, c, false);
}
#else
__device__ __forceinline__ float fdot2(half2_t a, half2_t b, float c) {
    return c + (float)a.x * (float)b.x + (float)a.y * (float)b.y;
}
#endif

// agent-scope (cross-XCD coherent) atomics for scan traffic
__device__ __forceinline__ uint ald(const uint* p) {
    return __hip_atomic_load(p, __ATOMIC_RELAXED, __HIP_MEMORY_SCOPE_AGENT);
}
__device__ __forceinline__ void ast(uint* p, uint v) {
    __hip_atomic_store(p, v, __ATOMIC_RELAXED, __HIP_MEMORY_SCOPE_AGENT);
}

__device__ __forceinline__ float sigmoidf_(float x) {
    return 1.f / (1.f + __expf(-x));
}

// Single-counter grid barrier: 1 arrival + 1 poller per block.
// RELEASE on arrival publishes this block's prior stores; RELAXED polling
// (no per-poll invalidate), one ACQUIRE after exit.
__device__ __forceinline__ void gbar(uint* cnt, uint target, int tid) {
    __syncthreads();                      // drain block's stores (vmcnt) first
    if (tid == 0) {
        __hip_atomic_fetch_add(cnt, 1u, __ATOMIC_RELEASE, __HIP_MEMORY_SCOPE_AGENT);
        int it = 0;
        while (__hip_atomic_load(cnt, __ATOMIC_RELAXED, __HIP_MEMORY_SCOPE_AGENT) < target) {
            if (++it > (1 << 22)) break;  // bounded: fail loud, not hang
            __builtin_amdgcn_s_sleep(2);
        }
        (void)__hip_atomic_load(cnt, __ATOMIC_ACQUIRE, __HIP_MEMORY_SCOPE_AGENT);
    }
    __syncthreads();
}

// ---------------------------------------------------------------------------
// P = We2h @ W  for r and z gates
// ---------------------------------------------------------------------------
__global__ void comp_p(const float* __restrict__ We2h, const float* __restrict__ Wre,
                       const float* __restrict__ Wze,
                       float* __restrict__ Pr, float* __restrict__ Pz) {
    int tid = blockIdx.x * blockDim.x + threadIdx.x;   // 256*512
    if (tid >= 256 * 512) return;
    int k = tid >> 9, j = tid & 511;
    float ar = 0.f, az = 0.f;
    for (int kk = 0; kk < 512; kk++) {
        float e = We2h[k * 512 + kk];
        ar += e * Wre[kk * 512 + j];
        az += e * Wze[kk * 512 + j];
    }
    Pr[tid] = ar;
    Pz[tid] = az;
}

// ---------------------------------------------------------------------------
// Build bf16 weights for the big GEMMs.
// ---------------------------------------------------------------------------
__global__ void build_wt(const float* __restrict__ We2h, const float* __restrict__ Wrx,
                         const float* __restrict__ Wzx, const float* __restrict__ Wnx,
                         const float* __restrict__ Pr, const float* __restrict__ Pz,
                         const float* __restrict__ br, const float* __restrict__ bz,
                         const float* __restrict__ bn, const float* __restrict__ Wo,
                         unsigned short* __restrict__ WcatT, float* __restrict__ biascat,
                         unsigned short* __restrict__ WoT) {
    int tid = blockIdx.x * blockDim.x + threadIdx.x;
    const int total1 = 2048 * 256;
    if (tid < total1) {
        int n = tid >> 8, k = tid & 255;
        int sel = n >> 9, nl = n & 511;
        float v;
        if (sel == 0)      v = We2h[k * 512 + nl];
        else if (sel == 1) v = Wrx[k * 512 + nl] + Pr[k * 512 + nl];
        else if (sel == 2) v = Wzx[k * 512 + nl] + Pz[k * 512 + nl];
        else               v = Wnx[k * 512 + nl];
        WcatT[tid] = f32_to_bf16(v);
        if (k == 0) {
            float bv = sel == 0 ? 0.f : sel == 1 ? br[nl] : sel == 2 ? bz[nl] : bn[nl];
            biascat[n] = bv;
        }
    } else {
        int t2 = tid - total1;
        if (t2 < 256 * 512) {
            int n = t2 >> 9, k = t2 & 511;
            WoT[t2] = f32_to_bf16(Wo[k * 256 + n]);
        }
    }
}

// ---------------------------------------------------------------------------
// Packed f16 recurrent weights (transformed):
//  warz uint2 [256 kp][512 j]: {pkh2(Ar[2kp],Ar[2kp+1]), pkh2(Az...)}, A=Wh-We
//  wan  uint  [512 k][512 j]:  pkh2(An[k][j], Wne[k][j]),  An = Wnh - Wne
// ---------------------------------------------------------------------------
__global__ void build_wscan(const float* __restrict__ Wrh, const float* __restrict__ Wre,
                            const float* __restrict__ Wzh, const float* __restrict__ Wze,
                            const float* __restrict__ Wnh, const float* __restrict__ Wne,
                            uint2* __restrict__ warz, uint* __restrict__ wan) {
    int tid = blockIdx.x * blockDim.x + threadIdx.x;
    if (tid < 256 * 512) {
        int kp = tid >> 9, j = tid & 511;
        int k0 = 2 * kp;
        float ar0 = Wrh[k0 * 512 + j] - Wre[k0 * 512 + j];
        float ar1 = Wrh[(k0 + 1) * 512 + j] - Wre[(k0 + 1) * 512 + j];
        float az0 = Wzh[k0 * 512 + j] - Wze[k0 * 512 + j];
        float az1 = Wzh[(k0 + 1) * 512 + j] - Wze[(k0 + 1) * 512 + j];
        warz[tid] = make_uint2(pkh2(ar0, ar1), pkh2(az0, az1));
    }
    int t2 = tid - 256 * 512;
    if (t2 >= 0 && t2 < 512 * 512) {
        int k = t2 >> 9, j = t2 & 511;
        float an = Wnh[k * 512 + j] - Wne[k * 512 + j];
        wan[t2] = pkh2(an, Wne[k * 512 + j]);
    }
}

// ---------------------------------------------------------------------------
// init hbuf: [256 kp][64 m] uint = (f16 h[m][2kp], f16 h[m][2kp+1])
// ---------------------------------------------------------------------------
__global__ void init_hbuf(const float* __restrict__ h0, uint* __restrict__ hbuf) {
    int tid = blockIdx.x * blockDim.x + threadIdx.x;   // 256*64
    if (tid >= 256 * 64) return;
    int kp = tid >> 6, m = tid & 63;
    hbuf[tid] = pkh2(h0[m * 512 + 2 * kp], h0[m * 512 + 2 * kp + 1]);
}

// ---------------------------------------------------------------------------
// GEMM-X: writes xproj directly in scan layout xT[t][col][m] bf16.
// ---------------------------------------------------------------------------
__global__ __launch_bounds__(256)
void gemmx_kernel(const float* __restrict__ A, const unsigned short* __restrict__ BT,
                  const float* __restrict__ bias, unsigned short* __restrict__ xT) {
    __shared__ unsigned short Asm[128 * 64];
    __shared__ unsigned short Bsm[128 * 64];
    __shared__ unsigned short Csm[128][128];   // [col][row]
    const int tid = threadIdx.x;
    const int t0 = blockIdx.x * 2;        // time-pair
    const int c0 = blockIdx.y * 128;      // col tile
    const int lane = tid & 63, wid = tid >> 6;
    const int wm = wid >> 1, wn = wid & 1;
    const int lr = lane & 15, lg = lane >> 4;

    f32x4 acc[4][4] = {};

    const int srow = tid >> 1, shalf = tid & 1;
    const int rowA = (srow & 63) * 512 + t0 + (srow >> 6);     // (b,t) -> A row
    const float* Arow = A + (size_t)rowA * 256 + shalf * 32;
    const unsigned short* Brow = BT + (size_t)(c0 + srow) * 256 + shalf * 32;
    unsigned short* As = &Asm[srow * 64 + shalf * 32];
    unsigned short* Bs = &Bsm[srow * 64 + shalf * 32];

    for (int kt = 0; kt < 256; kt += 64) {
#pragma unroll
        for (int q = 0; q < 8; q++) {
            float4 v = *(const float4*)(Arow + kt + q * 4);
            unsigned p0 = ((unsigned)f32_to_bf16(v.y) << 16) | f32_to_bf16(v.x);
            unsigned p1 = ((unsigned)f32_to_bf16(v.w) << 16) | f32_to_bf16(v.z);
            *(uint2*)(As + q * 4) = make_uint2(p0, p1);
        }
#pragma unroll
        for (int q = 0; q < 4; q++) {
            uint4 v = *(const uint4*)(Brow + kt + q * 8);
            *(uint4*)(Bs + q * 8) = v;
        }
        __syncthreads();
#pragma unroll
        for (int ks = 0; ks < 2; ks++) {
            bf16x8 af[4], bfr[4];
#pragma unroll
            for (int m = 0; m < 4; m++)
                af[m] = *(const bf16x8*)&Asm[(wm * 64 + m * 16 + lr) * 64 + ks * 32 + lg * 8];
#pragma unroll
            for (int n2 = 0; n2 < 4; n2++)
                bfr[n2] = *(const bf16x8*)&Bsm[(wn * 64 + n2 * 16 + lr) * 64 + ks * 32 + lg * 8];
#pragma unroll
            for (int m = 0; m < 4; m++)
#pragma unroll
                for (int n2 = 0; n2 < 4; n2++)
                    acc[m][n2] = __builtin_amdgcn_mfma_f32_16x16x32_bf16(
                        af[m], bfr[n2], acc[m][n2], 0, 0, 0);
        }
        __syncthreads();
    }
#pragma unroll
    for (int m = 0; m < 4; m++) {
        int r0 = wm * 64 + m * 16 + lg * 4;
#pragma unroll
        for (int n2 = 0; n2 < 4; n2++) {
            int c = wn * 64 + n2 * 16 + lr;
            float bv = bias[c0 + c];
#pragma unroll
            for (int i = 0; i < 4; i++)
                Csm[c][r0 + i] = f32_to_bf16(acc[m][n2][i] + bv);
        }
    }
    __syncthreads();
#pragma unroll
    for (int th = 0; th < 2; th++) {
        uint4* dst = (uint4*)(xT + ((size_t)(t0 + th) * 2048 + c0) * 64);
        for (int q = tid; q < 1024; q += 256) {
            int c = q >> 3, b0 = (q & 7) * 8;
            dst[q] = *(const uint4*)&Csm[c][th * 64 + b0];
        }
        __syncthreads();
    }
}

// ---------------------------------------------------------------------------
// Readout GEMM: A fp32 [M][K], BT bf16 [N][K], C fp32 + bias.
// ---------------------------------------------------------------------------
__global__ __launch_bounds__(256)
void gemm_out_kernel(const float* __restrict__ A, const unsigned short* __restrict__ BT,
                     const float* __restrict__ bias, float* __restrict__ C,
                     int M, int N, int K) {
    __shared__ unsigned short Asm[128 * 64];
    __shared__ unsigned short Bsm[128 * 64];
    const int tid = threadIdx.x;
    const int bm = blockIdx.x, bn = blockIdx.y;
    const int lane = tid & 63, wid = tid >> 6;
    const int wm = wid >> 1, wn = wid & 1;
    const int lr = lane & 15, lg = lane >> 4;

    f32x4 acc[4][4] = {};

    const int srow = tid >> 1, shalf = tid & 1;
    const float* Arow = A + (size_t)(bm * 128 + srow) * K + shalf * 32;
    const unsigned short* Brow = BT + (size_t)(bn * 128 + srow) * K + shalf * 32;
    unsigned short* As = &Asm[srow * 64 + shalf * 32];
    unsigned short* Bs = &Bsm[srow * 64 + shalf * 32];

    for (int kt = 0; kt < K; kt += 64) {
#pragma unroll
        for (int q = 0; q < 8; q++) {
            float4 v = *(const float4*)(Arow + kt + q * 4);
            unsigned p0 = ((unsigned)f32_to_bf16(v.y) << 16) | f32_to_bf16(v.x);
            unsigned p1 = ((unsigned)f32_to_bf16(v.w) << 16) | f32_to_bf16(v.z);
            *(uint2*)(As + q * 4) = make_uint2(p0, p1);
        }
#pragma unroll
        for (int q = 0; q < 4; q++) {
            uint4 v = *(const uint4*)(Brow + kt + q * 8);
            *(uint4*)(Bs + q * 8) = v;
        }
        __syncthreads();
#pragma unroll
        for (int ks = 0; ks < 2; ks++) {
            bf16x8 af[4], bfr[4];
#pragma unroll
            for (int m = 0; m < 4; m++)
                af[m] = *(const bf16x8*)&Asm[(wm * 64 + m * 16 + lr) * 64 + ks * 32 + lg * 8];
#pragma unroll
            for (int n2 = 0; n2 < 4; n2++)
                bfr[n2] = *(const bf16x8*)&Bsm[(wn * 64 + n2 * 16 + lr) * 64 + ks * 32 + lg * 8];
#pragma unroll
            for (int m = 0; m < 4; m++)
#pragma unroll
                for (int n2 = 0; n2 < 4; n2++)
                    acc[m][n2] = __builtin_amdgcn_mfma_f32_16x16x32_bf16(
                        af[m], bfr[n2], acc[m][n2], 0, 0, 0);
        }
        __syncthreads();
    }
#pragma unroll
    for (int m = 0; m < 4; m++) {
        int row0 = bm * 128 + wm * 64 + m * 16 + lg * 4;
#pragma unroll
        for (int n2 = 0; n2 < 4; n2++) {
            int col = bn * 128 + wn * 64 + n2 * 16 + lr;
            float bv = bias[col];
#pragma unroll
            for (int i = 0; i < 4; i++)
                C[(size_t)(row0 + i) * N + col] = acc[m][n2][i] + bv;
        }
    }
}

// ---------------------------------------------------------------------------
// Grid-synced weight-stationary scan. 64 blocks x 512 threads; block owns
// j = bid*8..+8. Cheap single-counter barrier (1 arrival + 1 poller / block).
// ---------------------------------------------------------------------------
__global__ __launch_bounds__(512)
void scan_sync(const unsigned short* __restrict__ xT,   // [512 t][2048 col][64 m] bf16
               const float* __restrict__ h0,            // [64 m][512 j]
               const uint2* __restrict__ warz,          // [256 kp][512 j]
               const uint* __restrict__ wan,            // [512 k][512 j]
               uint* __restrict__ hbuf,                 // [256 kp][64 m]
               uint* __restrict__ rhrxe,                // [512 k][64 m]
               uint* __restrict__ cnts,                 // [2] monotonic counters
               float* __restrict__ hseq)                // [64 m][512 t][512 j]
{
    __shared__ uint2 Wrz_l[256][JO];                    // 16 KB
    __shared__ uint  Wn_l[512][JO];                     // 16 KB
    __shared__ float part[3][8][JO][64];                // 48 KB
    __shared__ float h_loc[JO][64], z_loc[JO][64];      // 4 KB

    const int bid = blockIdx.x, tid = threadIdx.x;
    const int lane = tid & 63, wv = tid >> 6;           // 8 waves
    const int j0 = bid * JO;
    const int jF = tid >> 6, mF = tid & 63;             // finalize mapping

    uint* cnt0 = cnts;
    uint* cnt1 = cnts + 32;

    // one-time: weights -> LDS, local h slice
    for (int i = tid; i < 256 * JO; i += 512) {
        int kp = i >> 3, j = i & 7;
        Wrz_l[kp][j] = warz[kp * 512 + j0 + j];
    }
    for (int i = tid; i < 512 * JO; i += 512) {
        int k = i >> 3, j = i & 7;
        Wn_l[k][j] = wan[k * 512 + j0 + j];
    }
    h_loc[jF][mF] = h0[mF * 512 + j0 + jF];
    __syncthreads();

    for (int t = 0; t < T_; t++) {
        // ---- phase A: r,z partial dots (wave wv covers kp = wv*32..+32) ----
        {
            uint hv[32];
#pragma unroll
            for (int q = 0; q < 32; q++)
                hv[q] = ald(&hbuf[(wv * 32 + q) * 64 + lane]);
            float ar[JO] = {}, az[JO] = {};
#pragma unroll
            for (int q = 0; q < 32; q++) {
                half2_t h2 = uph2(hv[q]);
#pragma unroll
                for (int j = 0; j < JO; j++) {
                    uint2 w = *(const uint2*)&Wrz_l[wv * 32 + q][j];
                    ar[j] = fdot2(h2, uph2(w.x), ar[j]);
                    az[j] = fdot2(h2, uph2(w.y), az[j]);
                }
            }
#pragma unroll
            for (int j = 0; j < JO; j++) {
                part[0][wv][j][lane] = ar[j];
                part[1][wv][j][lane] = az[j];
            }
        }
        __syncthreads();

        // ---- finalize A (all 512 threads; coalesced xT reads & rhrxe pub) --
        {
            int jg = j0 + jF;
            float sr = 0.f, sz = 0.f;
#pragma unroll
            for (int w = 0; w < 8; w++) { sr += part[0][w][jF][mF]; sz += part[1][w][jF][mF]; }
            float xr = bf16_to_f32(xT[((size_t)t * 2048 + 512 + jg) * 64 + mF]);
            float xz = bf16_to_f32(xT[((size_t)t * 2048 + 1024 + jg) * 64 + mF]);
            float xe = bf16_to_f32(xT[((size_t)t * 2048 + jg) * 64 + mF]);
            float r = sigmoidf_(xr + sr);
            float z = sigmoidf_(xz + sz);
            float h = h_loc[jF][mF];
            z_loc[jF][mF] = z;
            ast(&rhrxe[jg * 64 + mF], pkh2(r * h, r * xe));
        }
        // ---- barrier 1: all rhrxe published ----
        gbar(cnt0, (uint)(t + 1) * NBLK, tid);

        // ---- phase B: n partial dots (wave wv covers k = wv*64..+64) ----
        {
            float an[JO] = {};
#pragma unroll
            for (int ch = 0; ch < 2; ch++) {
                uint rv[32];
#pragma unroll
                for (int q = 0; q < 32; q++)
                    rv[q] = ald(&rhrxe[(wv * 64 + ch * 32 + q) * 64 + lane]);
#pragma unroll
                for (int q = 0; q < 32; q++) {
                    half2_t p2 = uph2(rv[q]);
#pragma unroll
                    for (int j = 0; j < JO; j++)
                        an[j] = fdot2(p2, uph2(Wn_l[wv * 64 + ch * 32 + q][j]), an[j]);
                }
            }
#pragma unroll
            for (int j = 0; j < JO; j++) part[2][wv][j][lane] = an[j];
        }
        __syncthreads();

        // ---- finalize B: tanh, h update ----
        {
            int jg = j0 + jF;
            float sn = 0.f;
#pragma unroll
            for (int w = 0; w < 8; w++) sn += part[2][w][jF][mF];
            float xn = bf16_to_f32(xT[((size_t)t * 2048 + 1536 + jg) * 64 + mF]);
            float nn = tanhf(xn + sn);
            float z = z_loc[jF][mF];
            float h = h_loc[jF][mF];
            h_loc[jF][mF] = (1.f - z) * h + z * nn;
        }
        __syncthreads();

        // ---- publish new h (f16 pairs) + write hseq (32B bursts) ----
        if (tid < (JO / 2) * 64) {
            int jp = tid >> 6, mh = tid & 63;
            ast(&hbuf[(bid * (JO / 2) + jp) * 64 + mh],
                pkh2(h_loc[2 * jp][mh], h_loc[2 * jp + 1][mh]));
        }
        {
            int js = tid & 7, ms = tid >> 3;
            hseq[((size_t)ms * 512 + t) * 512 + j0 + js] = h_loc[js][ms];
        }
        // ---- barrier 2: all h published ----
        gbar(cnt1, (uint)(t + 1) * NBLK, tid);
    }
}

// ---------------------------------------------------------------------------
extern "C" void kernel_launch(void* const* d_in, const int* in_sizes, int n_in,
                              void* d_out, int out_size, void* d_ws, size_t ws_size,
                              hipStream_t stream) {
    const float* x    = (const float*)d_in[0];
    const float* h0   = (const float*)d_in[1];
    const float* We2h = (const float*)d_in[2];
    const float* Wrx  = (const float*)d_in[3];
    const float* Wrh  = (const float*)d_in[4];
    const float* Wre  = (const float*)d_in[5];
    const float* br   = (const float*)d_in[6];
    const float* Wzx  = (const float*)d_in[7];
    const float* Wzh  = (const float*)d_in[8];
    const float* Wze  = (const float*)d_in[9];
    const float* bz   = (const float*)d_in[10];
    const float* Wnx  = (const float*)d_in[11];
    const float* Wnh  = (const float*)d_in[12];
    const float* Wne  = (const float*)d_in[13];
    const float* bn   = (const float*)d_in[14];
    const float* Wo   = (const float*)d_in[15];
    const float* bo   = (const float*)d_in[16];

    // workspace layout (bytes)
    char* w = (char*)d_ws;
    unsigned short* xT    = (unsigned short*)(w);                  // 134217728
    uint2*          warz  = (uint2*)(w + 134217728);               // 1048576
    uint*           wan   = (uint*)(w + 135266304);                // 1048576
    unsigned short* WcatT = (unsigned short*)(w + 136314880);      // 1048576
    unsigned short* WoT   = (unsigned short*)(w + 137363456);      // 262144
    float*          biascat = (float*)(w + 137625600);             // 8192
    float*          Pr    = (float*)(w + 137633792);               // 524288
    float*          Pz    = (float*)(w + 138158080);               // 524288
    uint*           hbuf  = (uint*)(w + 138682368);                // 65536
    uint*           rhrxe = (uint*)(w + 138747904);                // 131072
    uint*           cnts  = (uint*)(w + 138878976);                // 256

    float* out  = (float*)d_out;                    // [B,T,D]
    float* hseq = (float*)d_out + (size_t)M_ * D_;  // [B,T,H]

    hipMemsetAsync(cnts, 0, 256, stream);

    // 1. composite input weights + packed scan weights
    comp_p<<<(256 * 512 + 255) / 256, 256, 0, stream>>>(We2h, Wre, Wze, Pr, Pz);
    build_wt<<<(2048 * 256 + 256 * 512 + 255) / 256, 256, 0, stream>>>(
        We2h, Wrx, Wzx, Wnx, Pr, Pz, br, bz, bn, Wo, WcatT, biascat, WoT);
    build_wscan<<<(256 * 512 + 512 * 512 + 255) / 256, 256, 0, stream>>>(
        Wrh, Wre, Wzh, Wze, Wnh, Wne, warz, wan);
    init_hbuf<<<(256 * 64 + 255) / 256, 256, 0, stream>>>(h0, hbuf);

    // 2. pre-projections directly into xT[t][col][m]
    {
        dim3 grid(T_ / 2, 2048 / 128);
        gemmx_kernel<<<grid, 256, 0, stream>>>(x, WcatT, biascat, xT);
    }
    // 3. grid-synced scan -> hseq
    scan_sync<<<NBLK, 512, 0, stream>>>(xT, h0, warz, wan, hbuf, rhrxe, cnts, hseq);
    // 4. readout: [32768,512] @ [512,256] + bo -> out
    {
        dim3 grid(M_ / 128, D_ / 128);
        gemm_out_kernel<<<grid, 256, 0, stream>>>(hseq, WoT, bo, out, M_, D_, H_);
    }
}

// Round 6
// 5892.888 us; speedup vs baseline: 2.5157x; 1.3732x over previous
//
#include <hip/hip_runtime.h>
#include <hip/hip_bf16.h>
#include <hip/hip_fp16.h>

// Problem constants
#define B_ 64
#define T_ 512
#define D_ 256
#define H_ 512
#define M_ (B_*T_)          // 32768

#define NBLK 64             // scan blocks
#define JO 8                // hidden columns owned per scan block

typedef unsigned int uint;
typedef __attribute__((ext_vector_type(8))) short bf16x8;
typedef __attribute__((ext_vector_type(4))) float f32x4;
typedef _Float16 half_t;
typedef __attribute__((ext_vector_type(2))) _Float16 half2_t;

__device__ __forceinline__ unsigned short f32_to_bf16(float f) {
    unsigned u = __builtin_bit_cast(unsigned, f);
    unsigned r = (u + 0x7fffu + ((u >> 16) & 1u)) >> 16;
    return (unsigned short)r;
}
__device__ __forceinline__ float bf16_to_f32(unsigned short h) {
    unsigned u = ((unsigned)h) << 16;
    return __builtin_bit_cast(float, u);
}
__device__ __forceinline__ unsigned pkh2(float a, float b) {
    half2_t h; h.x = (half_t)a; h.y = (half_t)b;
    return __builtin_bit_cast(unsigned, h);
}
__device__ __forceinline__ half2_t uph2(unsigned u) {
    return __builtin_bit_cast(half2_t, u);
}

#if __has_builtin(__builtin_amdgcn_fdot2)
__device__ __forceinline__ float fdot2(half2_t a, half2_t b, float c) {
    return __builtin_amdgcn_fdot2(a, b, c, false);
}
#else
__device__ __forceinline__ float fdot2(half2_t a, half2_t b, float c) {
    return c + (float)a.x * (float)b.x + (float)a.y * (float)b.y;
}
#endif

// agent-scope (cross-XCD coherent, L2-bypassing) relaxed atomics
__device__ __forceinline__ uint ald(const uint* p) {
    return __hip_atomic_load(p, __ATOMIC_RELAXED, __HIP_MEMORY_SCOPE_AGENT);
}
__device__ __forceinline__ void ast(uint* p, uint v) {
    __hip_atomic_store(p, v, __ATOMIC_RELAXED, __HIP_MEMORY_SCOPE_AGENT);
}

__device__ __forceinline__ float sigmoidf_(float x) {
    return 1.f / (1.f + __expf(-x));
}

// Fence-free grid barrier. Safe because ALL cross-block data moves through
// agent-scope atomics (L2-bypassing, coherent at L3):
//   producer: __syncthreads (compiler emits s_waitcnt vmcnt(0) -> data ACKed
//   at L3) -> relaxed fetch_add. consumer: relaxed poll sees count -> data
//   already at L3; its atomic loads bypass any stale L2/L1 copies.
// No release (buffer_wbl2) / acquire (buffer_inv) full-cache ops.
__device__ __forceinline__ void gbar(uint* cnt, uint target, int tid) {
    __syncthreads();                      // drain this block's stores
    if (tid == 0) {
        asm volatile("s_waitcnt vmcnt(0)" ::: "memory");   // belt-and-braces
        __hip_atomic_fetch_add(cnt, 1u, __ATOMIC_RELAXED, __HIP_MEMORY_SCOPE_AGENT);
        int it = 0;
        while (__hip_atomic_load(cnt, __ATOMIC_RELAXED, __HIP_MEMORY_SCOPE_AGENT) < target) {
            if (++it > (1 << 22)) break;  // bounded: fail loud, not hang
            __builtin_amdgcn_s_sleep(1);
        }
    }
    __syncthreads();
}

// ---------------------------------------------------------------------------
// P = We2h @ W  for r and z gates
// ---------------------------------------------------------------------------
__global__ void comp_p(const float* __restrict__ We2h, const float* __restrict__ Wre,
                       const float* __restrict__ Wze,
                       float* __restrict__ Pr, float* __restrict__ Pz) {
    int tid = blockIdx.x * blockDim.x + threadIdx.x;   // 256*512
    if (tid >= 256 * 512) return;
    int k = tid >> 9, j = tid & 511;
    float ar = 0.f, az = 0.f;
    for (int kk = 0; kk < 512; kk++) {
        float e = We2h[k * 512 + kk];
        ar += e * Wre[kk * 512 + j];
        az += e * Wze[kk * 512 + j];
    }
    Pr[tid] = ar;
    Pz[tid] = az;
}

// ---------------------------------------------------------------------------
// Build bf16 weights for the big GEMMs.
// ---------------------------------------------------------------------------
__global__ void build_wt(const float* __restrict__ We2h, const float* __restrict__ Wrx,
                         const float* __restrict__ Wzx, const float* __restrict__ Wnx,
                         const float* __restrict__ Pr, const float* __restrict__ Pz,
                         const float* __restrict__ br, const float* __restrict__ bz,
                         const float* __restrict__ bn, const float* __restrict__ Wo,
                         unsigned short* __restrict__ WcatT, float* __restrict__ biascat,
                         unsigned short* __restrict__ WoT) {
    int tid = blockIdx.x * blockDim.x + threadIdx.x;
    const int total1 = 2048 * 256;
    if (tid < total1) {
        int n = tid >> 8, k = tid & 255;
        int sel = n >> 9, nl = n & 511;
        float v;
        if (sel == 0)      v = We2h[k * 512 + nl];
        else if (sel == 1) v = Wrx[k * 512 + nl] + Pr[k * 512 + nl];
        else if (sel == 2) v = Wzx[k * 512 + nl] + Pz[k * 512 + nl];
        else               v = Wnx[k * 512 + nl];
        WcatT[tid] = f32_to_bf16(v);
        if (k == 0) {
            float bv = sel == 0 ? 0.f : sel == 1 ? br[nl] : sel == 2 ? bz[nl] : bn[nl];
            biascat[n] = bv;
        }
    } else {
        int t2 = tid - total1;
        if (t2 < 256 * 512) {
            int n = t2 >> 9, k = t2 & 511;
            WoT[t2] = f32_to_bf16(Wo[k * 256 + n]);
        }
    }
}

// ---------------------------------------------------------------------------
// Packed f16 recurrent weights (transformed):
//  warz uint2 [256 kp][512 j]: {pkh2(Ar[2kp],Ar[2kp+1]), pkh2(Az...)}, A=Wh-We
//  wan  uint  [512 k][512 j]:  pkh2(An[k][j], Wne[k][j]),  An = Wnh - Wne
// ---------------------------------------------------------------------------
__global__ void build_wscan(const float* __restrict__ Wrh, const float* __restrict__ Wre,
                            const float* __restrict__ Wzh, const float* __restrict__ Wze,
                            const float* __restrict__ Wnh, const float* __restrict__ Wne,
                            uint2* __restrict__ warz, uint* __restrict__ wan) {
    int tid = blockIdx.x * blockDim.x + threadIdx.x;
    if (tid < 256 * 512) {
        int kp = tid >> 9, j = tid & 511;
        int k0 = 2 * kp;
        float ar0 = Wrh[k0 * 512 + j] - Wre[k0 * 512 + j];
        float ar1 = Wrh[(k0 + 1) * 512 + j] - Wre[(k0 + 1) * 512 + j];
        float az0 = Wzh[k0 * 512 + j] - Wze[k0 * 512 + j];
        float az1 = Wzh[(k0 + 1) * 512 + j] - Wze[(k0 + 1) * 512 + j];
        warz[tid] = make_uint2(pkh2(ar0, ar1), pkh2(az0, az1));
    }
    int t2 = tid - 256 * 512;
    if (t2 >= 0 && t2 < 512 * 512) {
        int k = t2 >> 9, j = t2 & 511;
        float an = Wnh[k * 512 + j] - Wne[k * 512 + j];
        wan[t2] = pkh2(an, Wne[k * 512 + j]);
    }
}

// ---------------------------------------------------------------------------
// init hbuf: [256 kp][64 m] uint = (f16 h[m][2kp], f16 h[m][2kp+1])
// ---------------------------------------------------------------------------
__global__ void init_hbuf(const float* __restrict__ h0, uint* __restrict__ hbuf) {
    int tid = blockIdx.x * blockDim.x + threadIdx.x;   // 256*64
    if (tid >= 256 * 64) return;
    int kp = tid >> 6, m = tid & 63;
    hbuf[tid] = pkh2(h0[m * 512 + 2 * kp], h0[m * 512 + 2 * kp + 1]);
}

// ---------------------------------------------------------------------------
// GEMM-X: writes xproj directly in scan layout xT[t][col][m] bf16.
// ---------------------------------------------------------------------------
__global__ __launch_bounds__(256)
void gemmx_kernel(const float* __restrict__ A, const unsigned short* __restrict__ BT,
                  const float* __restrict__ bias, unsigned short* __restrict__ xT) {
    __shared__ unsigned short Asm[128 * 64];
    __shared__ unsigned short Bsm[128 * 64];
    __shared__ unsigned short Csm[128][128];   // [col][row]
    const int tid = threadIdx.x;
    const int t0 = blockIdx.x * 2;        // time-pair
    const int c0 = blockIdx.y * 128;      // col tile
    const int lane = tid & 63, wid = tid >> 6;
    const int wm = wid >> 1, wn = wid & 1;
    const int lr = lane & 15, lg = lane >> 4;

    f32x4 acc[4][4] = {};

    const int srow = tid >> 1, shalf = tid & 1;
    const int rowA = (srow & 63) * 512 + t0 + (srow >> 6);     // (b,t) -> A row
    const float* Arow = A + (size_t)rowA * 256 + shalf * 32;
    const unsigned short* Brow = BT + (size_t)(c0 + srow) * 256 + shalf * 32;
    unsigned short* As = &Asm[srow * 64 + shalf * 32];
    unsigned short* Bs = &Bsm[srow * 64 + shalf * 32];

    for (int kt = 0; kt < 256; kt += 64) {
#pragma unroll
        for (int q = 0; q < 8; q++) {
            float4 v = *(const float4*)(Arow + kt + q * 4);
            unsigned p0 = ((unsigned)f32_to_bf16(v.y) << 16) | f32_to_bf16(v.x);
            unsigned p1 = ((unsigned)f32_to_bf16(v.w) << 16) | f32_to_bf16(v.z);
            *(uint2*)(As + q * 4) = make_uint2(p0, p1);
        }
#pragma unroll
        for (int q = 0; q < 4; q++) {
            uint4 v = *(const uint4*)(Brow + kt + q * 8);
            *(uint4*)(Bs + q * 8) = v;
        }
        __syncthreads();
#pragma unroll
        for (int ks = 0; ks < 2; ks++) {
            bf16x8 af[4], bfr[4];
#pragma unroll
            for (int m = 0; m < 4; m++)
                af[m] = *(const bf16x8*)&Asm[(wm * 64 + m * 16 + lr) * 64 + ks * 32 + lg * 8];
#pragma unroll
            for (int n2 = 0; n2 < 4; n2++)
                bfr[n2] = *(const bf16x8*)&Bsm[(wn * 64 + n2 * 16 + lr) * 64 + ks * 32 + lg * 8];
#pragma unroll
            for (int m = 0; m < 4; m++)
#pragma unroll
                for (int n2 = 0; n2 < 4; n2++)
                    acc[m][n2] = __builtin_amdgcn_mfma_f32_16x16x32_bf16(
                        af[m], bfr[n2], acc[m][n2], 0, 0, 0);
        }
        __syncthreads();
    }
#pragma unroll
    for (int m = 0; m < 4; m++) {
        int r0 = wm * 64 + m * 16 + lg * 4;
#pragma unroll
        for (int n2 = 0; n2 < 4; n2++) {
            int c = wn * 64 + n2 * 16 + lr;
            float bv = bias[c0 + c];
#pragma unroll
            for (int i = 0; i < 4; i++)
                Csm[c][r0 + i] = f32_to_bf16(acc[m][n2][i] + bv);
        }
    }
    __syncthreads();
#pragma unroll
    for (int th = 0; th < 2; th++) {
        uint4* dst = (uint4*)(xT + ((size_t)(t0 + th) * 2048 + c0) * 64);
        for (int q = tid; q < 1024; q += 256) {
            int c = q >> 3, b0 = (q & 7) * 8;
            dst[q] = *(const uint4*)&Csm[c][th * 64 + b0];
        }
        __syncthreads();
    }
}

// ---------------------------------------------------------------------------
// Readout GEMM: A fp32 [M][K], BT bf16 [N][K], C fp32 + bias.
// ---------------------------------------------------------------------------
__global__ __launch_bounds__(256)
void gemm_out_kernel(const float* __restrict__ A, const unsigned short* __restrict__ BT,
                     const float* __restrict__ bias, float* __restrict__ C,
                     int M, int N, int K) {
    __shared__ unsigned short Asm[128 * 64];
    __shared__ unsigned short Bsm[128 * 64];
    const int tid = threadIdx.x;
    const int bm = blockIdx.x, bn = blockIdx.y;
    const int lane = tid & 63, wid = tid >> 6;
    const int wm = wid >> 1, wn = wid & 1;
    const int lr = lane & 15, lg = lane >> 4;

    f32x4 acc[4][4] = {};

    const int srow = tid >> 1, shalf = tid & 1;
    const float* Arow = A + (size_t)(bm * 128 + srow) * K + shalf * 32;
    const unsigned short* Brow = BT + (size_t)(bn * 128 + srow) * K + shalf * 32;
    unsigned short* As = &Asm[srow * 64 + shalf * 32];
    unsigned short* Bs = &Bsm[srow * 64 + shalf * 32];

    for (int kt = 0; kt < K; kt += 64) {
#pragma unroll
        for (int q = 0; q < 8; q++) {
            float4 v = *(const float4*)(Arow + kt + q * 4);
            unsigned p0 = ((unsigned)f32_to_bf16(v.y) << 16) | f32_to_bf16(v.x);
            unsigned p1 = ((unsigned)f32_to_bf16(v.w) << 16) | f32_to_bf16(v.z);
            *(uint2*)(As + q * 4) = make_uint2(p0, p1);
        }
#pragma unroll
        for (int q = 0; q < 4; q++) {
            uint4 v = *(const uint4*)(Brow + kt + q * 8);
            *(uint4*)(Bs + q * 8) = v;
        }
        __syncthreads();
#pragma unroll
        for (int ks = 0; ks < 2; ks++) {
            bf16x8 af[4], bfr[4];
#pragma unroll
            for (int m = 0; m < 4; m++)
                af[m] = *(const bf16x8*)&Asm[(wm * 64 + m * 16 + lr) * 64 + ks * 32 + lg * 8];
#pragma unroll
            for (int n2 = 0; n2 < 4; n2++)
                bfr[n2] = *(const bf16x8*)&Bsm[(wn * 64 + n2 * 16 + lr) * 64 + ks * 32 + lg * 8];
#pragma unroll
            for (int m = 0; m < 4; m++)
#pragma unroll
                for (int n2 = 0; n2 < 4; n2++)
                    acc[m][n2] = __builtin_amdgcn_mfma_f32_16x16x32_bf16(
                        af[m], bfr[n2], acc[m][n2], 0, 0, 0);
        }
        __syncthreads();
    }
#pragma unroll
    for (int m = 0; m < 4; m++) {
        int row0 = bm * 128 + wm * 64 + m * 16 + lg * 4;
#pragma unroll
        for (int n2 = 0; n2 < 4; n2++) {
            int col = bn * 128 + wn * 64 + n2 * 16 + lr;
            float bv = bias[col];
#pragma unroll
            for (int i = 0; i < 4; i++)
                C[(size_t)(row0 + i) * N + col] = acc[m][n2][i] + bv;
        }
    }
}

// ---------------------------------------------------------------------------
// Grid-synced weight-stationary scan. 64 blocks x 512 threads; block owns
// j = bid*8..+8. Fence-free single-counter barriers.
// ---------------------------------------------------------------------------
__global__ __launch_bounds__(512)
void scan_sync(const unsigned short* __restrict__ xT,   // [512 t][2048 col][64 m] bf16
               const float* __restrict__ h0,            // [64 m][512 j]
               const uint2* __restrict__ warz,          // [256 kp][512 j]
               const uint* __restrict__ wan,            // [512 k][512 j]
               uint* __restrict__ hbuf,                 // [256 kp][64 m]
               uint* __restrict__ rhrxe,                // [512 k][64 m]
               uint* __restrict__ cnts,                 // monotonic counters
               float* __restrict__ hseq)                // [64 m][512 t][512 j]
{
    __shared__ uint2 Wrz_l[256][JO];                    // 16 KB
    __shared__ uint  Wn_l[512][JO];                     // 16 KB
    __shared__ float part[3][8][JO][64];                // 48 KB
    __shared__ float h_loc[JO][64], z_loc[JO][64];      // 4 KB

    const int bid = blockIdx.x, tid = threadIdx.x;
    const int lane = tid & 63, wv = tid >> 6;           // 8 waves
    const int j0 = bid * JO;
    const int jF = tid >> 6, mF = tid & 63;             // finalize mapping

    uint* cnt0 = cnts;
    uint* cnt1 = cnts + 32;

    // one-time: weights -> LDS, local h slice
    for (int i = tid; i < 256 * JO; i += 512) {
        int kp = i >> 3, j = i & 7;
        Wrz_l[kp][j] = warz[kp * 512 + j0 + j];
    }
    for (int i = tid; i < 512 * JO; i += 512) {
        int k = i >> 3, j = i & 7;
        Wn_l[k][j] = wan[k * 512 + j0 + j];
    }
    h_loc[jF][mF] = h0[mF * 512 + j0 + jF];
    __syncthreads();

    for (int t = 0; t < T_; t++) {
        // prefetch this step's xT gate values (independent of exchanges)
        const int jg = j0 + jF;
        const size_t xbase = (size_t)t * 2048 * 64;
        float xe = bf16_to_f32(xT[xbase + (size_t)jg * 64 + mF]);
        float xr = bf16_to_f32(xT[xbase + (size_t)(512 + jg) * 64 + mF]);
        float xz = bf16_to_f32(xT[xbase + (size_t)(1024 + jg) * 64 + mF]);
        float xn = bf16_to_f32(xT[xbase + (size_t)(1536 + jg) * 64 + mF]);

        // ---- phase A: r,z partial dots (wave wv covers kp = wv*32..+32) ----
        {
            uint hv[32];
#pragma unroll
            for (int q = 0; q < 32; q++)
                hv[q] = ald(&hbuf[(wv * 32 + q) * 64 + lane]);
            float ar[JO] = {}, az[JO] = {};
#pragma unroll
            for (int q = 0; q < 32; q++) {
                half2_t h2 = uph2(hv[q]);
#pragma unroll
                for (int j = 0; j < JO; j++) {
                    uint2 w = *(const uint2*)&Wrz_l[wv * 32 + q][j];
                    ar[j] = fdot2(h2, uph2(w.x), ar[j]);
                    az[j] = fdot2(h2, uph2(w.y), az[j]);
                }
            }
#pragma unroll
            for (int j = 0; j < JO; j++) {
                part[0][wv][j][lane] = ar[j];
                part[1][wv][j][lane] = az[j];
            }
        }
        __syncthreads();

        // ---- finalize A (all 512 threads; coalesced rhrxe publish) ----
        {
            float sr = 0.f, sz = 0.f;
#pragma unroll
            for (int w = 0; w < 8; w++) { sr += part[0][w][jF][mF]; sz += part[1][w][jF][mF]; }
            float r = sigmoidf_(xr + sr);
            float z = sigmoidf_(xz + sz);
            float h = h_loc[jF][mF];
            z_loc[jF][mF] = z;
            ast(&rhrxe[jg * 64 + mF], pkh2(r * h, r * xe));
        }
        // ---- barrier 1: all rhrxe published ----
        gbar(cnt0, (uint)(t + 1) * NBLK, tid);

        // ---- phase B: n partial dots (wave wv covers k = wv*64..+64) ----
        {
            float an[JO] = {};
#pragma unroll
            for (int ch = 0; ch < 2; ch++) {
                uint rv[32];
#pragma unroll
                for (int q = 0; q < 32; q++)
                    rv[q] = ald(&rhrxe[(wv * 64 + ch * 32 + q) * 64 + lane]);
#pragma unroll
                for (int q = 0; q < 32; q++) {
                    half2_t p2 = uph2(rv[q]);
#pragma unroll
                    for (int j = 0; j < JO; j++)
                        an[j] = fdot2(p2, uph2(Wn_l[wv * 64 + ch * 32 + q][j]), an[j]);
                }
            }
#pragma unroll
            for (int j = 0; j < JO; j++) part[2][wv][j][lane] = an[j];
        }
        __syncthreads();

        // ---- finalize B: tanh, h update ----
        {
            float sn = 0.f;
#pragma unroll
            for (int w = 0; w < 8; w++) sn += part[2][w][jF][mF];
            float nn = tanhf(xn + sn);
            float z = z_loc[jF][mF];
            float h = h_loc[jF][mF];
            h_loc[jF][mF] = (1.f - z) * h + z * nn;
        }
        __syncthreads();

        // ---- publish new h (f16 pairs) + write hseq (32B bursts) ----
        if (tid < (JO / 2) * 64) {
            int jp = tid >> 6, mh = tid & 63;
            ast(&hbuf[(bid * (JO / 2) + jp) * 64 + mh],
                pkh2(h_loc[2 * jp][mh], h_loc[2 * jp + 1][mh]));
        }
        {
            int js = tid & 7, ms = tid >> 3;
            hseq[((size_t)ms * 512 + t) * 512 + j0 + js] = h_loc[js][ms];
        }
        // ---- barrier 2: all h published ----
        gbar(cnt1, (uint)(t + 1) * NBLK, tid);
    }
}

// ---------------------------------------------------------------------------
extern "C" void kernel_launch(void* const* d_in, const int* in_sizes, int n_in,
                              void* d_out, int out_size, void* d_ws, size_t ws_size,
                              hipStream_t stream) {
    const float* x    = (const float*)d_in[0];
    const float* h0   = (const float*)d_in[1];
    const float* We2h = (const float*)d_in[2];
    const float* Wrx  = (const float*)d_in[3];
    const float* Wrh  = (const float*)d_in[4];
    const float* Wre  = (const float*)d_in[5];
    const float* br   = (const float*)d_in[6];
    const float* Wzx  = (const float*)d_in[7];
    const float* Wzh  = (const float*)d_in[8];
    const float* Wze  = (const float*)d_in[9];
    const float* bz   = (const float*)d_in[10];
    const float* Wnx  = (const float*)d_in[11];
    const float* Wnh  = (const float*)d_in[12];
    const float* Wne  = (const float*)d_in[13];
    const float* bn   = (const float*)d_in[14];
    const float* Wo   = (const float*)d_in[15];
    const float* bo   = (const float*)d_in[16];

    // workspace layout (bytes)
    char* w = (char*)d_ws;
    unsigned short* xT    = (unsigned short*)(w);                  // 134217728
    uint2*          warz  = (uint2*)(w + 134217728);               // 1048576
    uint*           wan   = (uint*)(w + 135266304);                // 1048576
    unsigned short* WcatT = (unsigned short*)(w + 136314880);      // 1048576
    unsigned short* WoT   = (unsigned short*)(w + 137363456);      // 262144
    float*          biascat = (float*)(w + 137625600);             // 8192
    float*          Pr    = (float*)(w + 137633792);               // 524288
    float*          Pz    = (float*)(w + 138158080);               // 524288
    uint*           hbuf  = (uint*)(w + 138682368);                // 65536
    uint*           rhrxe = (uint*)(w + 138747904);                // 131072
    uint*           cnts  = (uint*)(w + 138878976);                // 256

    float* out  = (float*)d_out;                    // [B,T,D]
    float* hseq = (float*)d_out + (size_t)M_ * D_;  // [B,T,H]

    hipMemsetAsync(cnts, 0, 256, stream);

    // 1. composite input weights + packed scan weights
    comp_p<<<(256 * 512 + 255) / 256, 256, 0, stream>>>(We2h, Wre, Wze, Pr, Pz);
    build_wt<<<(2048 * 256 + 256 * 512 + 255) / 256, 256, 0, stream>>>(
        We2h, Wrx, Wzx, Wnx, Pr, Pz, br, bz, bn, Wo, WcatT, biascat, WoT);
    build_wscan<<<(256 * 512 + 512 * 512 + 255) / 256, 256, 0, stream>>>(
        Wrh, Wre, Wzh, Wze, Wnh, Wne, warz, wan);
    init_hbuf<<<(256 * 64 + 255) / 256, 256, 0, stream>>>(h0, hbuf);

    // 2. pre-projections directly into xT[t][col][m]
    {
        dim3 grid(T_ / 2, 2048 / 128);
        gemmx_kernel<<<grid, 256, 0, stream>>>(x, WcatT, biascat, xT);
    }
    // 3. grid-synced scan -> hseq
    scan_sync<<<NBLK, 512, 0, stream>>>(xT, h0, warz, wan, hbuf, rhrxe, cnts, hseq);
    // 4. readout: [32768,512] @ [512,256] + bo -> out
    {
        dim3 grid(M_ / 128, D_ / 128);
        gemm_out_kernel<<<grid, 256, 0, stream>>>(hseq, WoT, bo, out, M_, D_, H_);
    }
}

// Round 7
// 5689.529 us; speedup vs baseline: 2.6057x; 1.0357x over previous
//
#include <hip/hip_runtime.h>
#include <hip/hip_bf16.h>
#include <hip/hip_fp16.h>

// Problem constants
#define B_ 64
#define T_ 512
#define D_ 256
#define H_ 512
#define M_ (B_*T_)          // 32768

#define NBLK 64             // scan blocks
#define JO 8                // hidden columns owned per scan block
#define BAR_STRIDE 2048     // uints per barrier set

typedef unsigned int uint;
typedef __attribute__((ext_vector_type(8))) short bf16x8;
typedef __attribute__((ext_vector_type(4))) float f32x4;
typedef _Float16 half_t;
typedef __attribute__((ext_vector_type(2))) _Float16 half2_t;

__device__ __forceinline__ unsigned short f32_to_bf16(float f) {
    unsigned u = __builtin_bit_cast(unsigned, f);
    unsigned r = (u + 0x7fffu + ((u >> 16) & 1u)) >> 16;
    return (unsigned short)r;
}
__device__ __forceinline__ float bf16_to_f32(unsigned short h) {
    unsigned u = ((unsigned)h) << 16;
    return __builtin_bit_cast(float, u);
}
__device__ __forceinline__ unsigned pkh2(float a, float b) {
    half2_t h; h.x = (half_t)a; h.y = (half_t)b;
    return __builtin_bit_cast(unsigned, h);
}
__device__ __forceinline__ half2_t uph2(unsigned u) {
    return __builtin_bit_cast(half2_t, u);
}

#if __has_builtin(__builtin_amdgcn_fdot2)
__device__ __forceinline__ float fdot2(half2_t a, half2_t b, float c) {
    return __builtin_amdgcn_fdot2(a, b, c, false);
}
#else
__device__ __forceinline__ float fdot2(half2_t a, half2_t b, float c) {
    return c + (float)a.x * (float)b.x + (float)a.y * (float)b.y;
}
#endif

// agent-scope (cross-XCD coherent, L2-bypassing) relaxed atomics
__device__ __forceinline__ uint ald(const uint* p) {
    return __hip_atomic_load(p, __ATOMIC_RELAXED, __HIP_MEMORY_SCOPE_AGENT);
}
__device__ __forceinline__ void ast(uint* p, uint v) {
    __hip_atomic_store(p, v, __ATOMIC_RELAXED, __HIP_MEMORY_SCOPE_AGENT);
}

__device__ __forceinline__ float sigmoidf_(float x) {
    return 1.f / (1.f + __expf(-x));
}

// Hierarchical fence-free grid barrier for 64 blocks (8 groups x 8).
// Layout within a set (uint indices, 256B line spacing):
//   sub[g]  at base[g*64]    -- arrival counters, 8 RMWs each, NO readers
//   root    at base[512]     -- 8 RMWs (group-lasts), no readers
//   epoch[g] at base[640+g*64] -- written once/step by root-last, 8 pollers each
// Monotonic counters; per-step targets derived from t. Causality: epoch=t+1
// is RMW-chained after all 64 arrivals, each after that block's vmcnt(0)-
// drained data stores; all cross-block data moves via agent-scope atomics
// (L2-bypassing), so no cache fences are needed.
__device__ __forceinline__ void gbar2(uint* base, uint t, int tid, int bid) {
    __syncthreads();                      // drain this block's stores
    if (tid == 0) {
        asm volatile("s_waitcnt vmcnt(0)" ::: "memory");   // belt-and-braces
        const uint g = (uint)bid & 7u;
        uint old = __hip_atomic_fetch_add(&base[g * 64], 1u,
                      __ATOMIC_RELAXED, __HIP_MEMORY_SCOPE_AGENT);
        if (old == t * 8u + 7u) {         // last arrival in my group this step
            uint r = __hip_atomic_fetch_add(&base[512], 1u,
                      __ATOMIC_RELAXED, __HIP_MEMORY_SCOPE_AGENT);
            if (r == t * 8u + 7u) {       // last group overall
#pragma unroll
                for (int e = 0; e < 8; e++)
                    __hip_atomic_store(&base[640 + e * 64], t + 1u,
                      __ATOMIC_RELAXED, __HIP_MEMORY_SCOPE_AGENT);
            }
        }
        int it = 0;
        while (__hip_atomic_load(&base[640 + g * 64],
                 __ATOMIC_RELAXED, __HIP_MEMORY_SCOPE_AGENT) < t + 1u) {
            if (++it > (1 << 22)) break;  // bounded: fail loud, not hang
            __builtin_amdgcn_s_sleep(2);
        }
    }
    __syncthreads();
}

// ---------------------------------------------------------------------------
// P = We2h @ W  for r and z gates
// ---------------------------------------------------------------------------
__global__ void comp_p(const float* __restrict__ We2h, const float* __restrict__ Wre,
                       const float* __restrict__ Wze,
                       float* __restrict__ Pr, float* __restrict__ Pz) {
    int tid = blockIdx.x * blockDim.x + threadIdx.x;   // 256*512
    if (tid >= 256 * 512) return;
    int k = tid >> 9, j = tid & 511;
    float ar = 0.f, az = 0.f;
    for (int kk = 0; kk < 512; kk++) {
        float e = We2h[k * 512 + kk];
        ar += e * Wre[kk * 512 + j];
        az += e * Wze[kk * 512 + j];
    }
    Pr[tid] = ar;
    Pz[tid] = az;
}

// ---------------------------------------------------------------------------
// Build bf16 weights for the big GEMMs.
// ---------------------------------------------------------------------------
__global__ void build_wt(const float* __restrict__ We2h, const float* __restrict__ Wrx,
                         const float* __restrict__ Wzx, const float* __restrict__ Wnx,
                         const float* __restrict__ Pr, const float* __restrict__ Pz,
                         const float* __restrict__ br, const float* __restrict__ bz,
                         const float* __restrict__ bn, const float* __restrict__ Wo,
                         unsigned short* __restrict__ WcatT, float* __restrict__ biascat,
                         unsigned short* __restrict__ WoT) {
    int tid = blockIdx.x * blockDim.x + threadIdx.x;
    const int total1 = 2048 * 256;
    if (tid < total1) {
        int n = tid >> 8, k = tid & 255;
        int sel = n >> 9, nl = n & 511;
        float v;
        if (sel == 0)      v = We2h[k * 512 + nl];
        else if (sel == 1) v = Wrx[k * 512 + nl] + Pr[k * 512 + nl];
        else if (sel == 2) v = Wzx[k * 512 + nl] + Pz[k * 512 + nl];
        else               v = Wnx[k * 512 + nl];
        WcatT[tid] = f32_to_bf16(v);
        if (k == 0) {
            float bv = sel == 0 ? 0.f : sel == 1 ? br[nl] : sel == 2 ? bz[nl] : bn[nl];
            biascat[n] = bv;
        }
    } else {
        int t2 = tid - total1;
        if (t2 < 256 * 512) {
            int n = t2 >> 9, k = t2 & 511;
            WoT[t2] = f32_to_bf16(Wo[k * 256 + n]);
        }
    }
}

// ---------------------------------------------------------------------------
// Packed f16 recurrent weights (transformed):
//  warz uint2 [256 kp][512 j]: {pkh2(Ar[2kp],Ar[2kp+1]), pkh2(Az...)}, A=Wh-We
//  wan  uint  [512 k][512 j]:  pkh2(An[k][j], Wne[k][j]),  An = Wnh - Wne
// ---------------------------------------------------------------------------
__global__ void build_wscan(const float* __restrict__ Wrh, const float* __restrict__ Wre,
                            const float* __restrict__ Wzh, const float* __restrict__ Wze,
                            const float* __restrict__ Wnh, const float* __restrict__ Wne,
                            uint2* __restrict__ warz, uint* __restrict__ wan) {
    int tid = blockIdx.x * blockDim.x + threadIdx.x;
    if (tid < 256 * 512) {
        int kp = tid >> 9, j = tid & 511;
        int k0 = 2 * kp;
        float ar0 = Wrh[k0 * 512 + j] - Wre[k0 * 512 + j];
        float ar1 = Wrh[(k0 + 1) * 512 + j] - Wre[(k0 + 1) * 512 + j];
        float az0 = Wzh[k0 * 512 + j] - Wze[k0 * 512 + j];
        float az1 = Wzh[(k0 + 1) * 512 + j] - Wze[(k0 + 1) * 512 + j];
        warz[tid] = make_uint2(pkh2(ar0, ar1), pkh2(az0, az1));
    }
    int t2 = tid - 256 * 512;
    if (t2 >= 0 && t2 < 512 * 512) {
        int k = t2 >> 9, j = t2 & 511;
        float an = Wnh[k * 512 + j] - Wne[k * 512 + j];
        wan[t2] = pkh2(an, Wne[k * 512 + j]);
    }
}

// ---------------------------------------------------------------------------
// init hbuf: [256 kp][64 m] uint = (f16 h[m][2kp], f16 h[m][2kp+1])
// ---------------------------------------------------------------------------
__global__ void init_hbuf(const float* __restrict__ h0, uint* __restrict__ hbuf) {
    int tid = blockIdx.x * blockDim.x + threadIdx.x;   // 256*64
    if (tid >= 256 * 64) return;
    int kp = tid >> 6, m = tid & 63;
    hbuf[tid] = pkh2(h0[m * 512 + 2 * kp], h0[m * 512 + 2 * kp + 1]);
}

// ---------------------------------------------------------------------------
// GEMM-X: writes xproj directly in scan layout xT[t][col][m] bf16.
// ---------------------------------------------------------------------------
__global__ __launch_bounds__(256)
void gemmx_kernel(const float* __restrict__ A, const unsigned short* __restrict__ BT,
                  const float* __restrict__ bias, unsigned short* __restrict__ xT) {
    __shared__ unsigned short Asm[128 * 64];
    __shared__ unsigned short Bsm[128 * 64];
    __shared__ unsigned short Csm[128][128];   // [col][row]
    const int tid = threadIdx.x;
    const int t0 = blockIdx.x * 2;        // time-pair
    const int c0 = blockIdx.y * 128;      // col tile
    const int lane = tid & 63, wid = tid >> 6;
    const int wm = wid >> 1, wn = wid & 1;
    const int lr = lane & 15, lg = lane >> 4;

    f32x4 acc[4][4] = {};

    const int srow = tid >> 1, shalf = tid & 1;
    const int rowA = (srow & 63) * 512 + t0 + (srow >> 6);     // (b,t) -> A row
    const float* Arow = A + (size_t)rowA * 256 + shalf * 32;
    const unsigned short* Brow = BT + (size_t)(c0 + srow) * 256 + shalf * 32;
    unsigned short* As = &Asm[srow * 64 + shalf * 32];
    unsigned short* Bs = &Bsm[srow * 64 + shalf * 32];

    for (int kt = 0; kt < 256; kt += 64) {
#pragma unroll
        for (int q = 0; q < 8; q++) {
            float4 v = *(const float4*)(Arow + kt + q * 4);
            unsigned p0 = ((unsigned)f32_to_bf16(v.y) << 16) | f32_to_bf16(v.x);
            unsigned p1 = ((unsigned)f32_to_bf16(v.w) << 16) | f32_to_bf16(v.z);
            *(uint2*)(As + q * 4) = make_uint2(p0, p1);
        }
#pragma unroll
        for (int q = 0; q < 4; q++) {
            uint4 v = *(const uint4*)(Brow + kt + q * 8);
            *(uint4*)(Bs + q * 8) = v;
        }
        __syncthreads();
#pragma unroll
        for (int ks = 0; ks < 2; ks++) {
            bf16x8 af[4], bfr[4];
#pragma unroll
            for (int m = 0; m < 4; m++)
                af[m] = *(const bf16x8*)&Asm[(wm * 64 + m * 16 + lr) * 64 + ks * 32 + lg * 8];
#pragma unroll
            for (int n2 = 0; n2 < 4; n2++)
                bfr[n2] = *(const bf16x8*)&Bsm[(wn * 64 + n2 * 16 + lr) * 64 + ks * 32 + lg * 8];
#pragma unroll
            for (int m = 0; m < 4; m++)
#pragma unroll
                for (int n2 = 0; n2 < 4; n2++)
                    acc[m][n2] = __builtin_amdgcn_mfma_f32_16x16x32_bf16(
                        af[m], bfr[n2], acc[m][n2], 0, 0, 0);
        }
        __syncthreads();
    }
#pragma unroll
    for (int m = 0; m < 4; m++) {
        int r0 = wm * 64 + m * 16 + lg * 4;
#pragma unroll
        for (int n2 = 0; n2 < 4; n2++) {
            int c = wn * 64 + n2 * 16 + lr;
            float bv = bias[c0 + c];
#pragma unroll
            for (int i = 0; i < 4; i++)
                Csm[c][r0 + i] = f32_to_bf16(acc[m][n2][i] + bv);
        }
    }
    __syncthreads();
#pragma unroll
    for (int th = 0; th < 2; th++) {
        uint4* dst = (uint4*)(xT + ((size_t)(t0 + th) * 2048 + c0) * 64);
        for (int q = tid; q < 1024; q += 256) {
            int c = q >> 3, b0 = (q & 7) * 8;
            dst[q] = *(const uint4*)&Csm[c][th * 64 + b0];
        }
        __syncthreads();
    }
}

// ---------------------------------------------------------------------------
// Readout GEMM: A fp32 [M][K], BT bf16 [N][K], C fp32 + bias.
// ---------------------------------------------------------------------------
__global__ __launch_bounds__(256)
void gemm_out_kernel(const float* __restrict__ A, const unsigned short* __restrict__ BT,
                     const float* __restrict__ bias, float* __restrict__ C,
                     int M, int N, int K) {
    __shared__ unsigned short Asm[128 * 64];
    __shared__ unsigned short Bsm[128 * 64];
    const int tid = threadIdx.x;
    const int bm = blockIdx.x, bn = blockIdx.y;
    const int lane = tid & 63, wid = tid >> 6;
    const int wm = wid >> 1, wn = wid & 1;
    const int lr = lane & 15, lg = lane >> 4;

    f32x4 acc[4][4] = {};

    const int srow = tid >> 1, shalf = tid & 1;
    const float* Arow = A + (size_t)(bm * 128 + srow) * K + shalf * 32;
    const unsigned short* Brow = BT + (size_t)(bn * 128 + srow) * K + shalf * 32;
    unsigned short* As = &Asm[srow * 64 + shalf * 32];
    unsigned short* Bs = &Bsm[srow * 64 + shalf * 32];

    for (int kt = 0; kt < K; kt += 64) {
#pragma unroll
        for (int q = 0; q < 8; q++) {
            float4 v = *(const float4*)(Arow + kt + q * 4);
            unsigned p0 = ((unsigned)f32_to_bf16(v.y) << 16) | f32_to_bf16(v.x);
            unsigned p1 = ((unsigned)f32_to_bf16(v.w) << 16) | f32_to_bf16(v.z);
            *(uint2*)(As + q * 4) = make_uint2(p0, p1);
        }
#pragma unroll
        for (int q = 0; q < 4; q++) {
            uint4 v = *(const uint4*)(Brow + kt + q * 8);
            *(uint4*)(Bs + q * 8) = v;
        }
        __syncthreads();
#pragma unroll
        for (int ks = 0; ks < 2; ks++) {
            bf16x8 af[4], bfr[4];
#pragma unroll
            for (int m = 0; m < 4; m++)
                af[m] = *(const bf16x8*)&Asm[(wm * 64 + m * 16 + lr) * 64 + ks * 32 + lg * 8];
#pragma unroll
            for (int n2 = 0; n2 < 4; n2++)
                bfr[n2] = *(const bf16x8*)&Bsm[(wn * 64 + n2 * 16 + lr) * 64 + ks * 32 + lg * 8];
#pragma unroll
            for (int m = 0; m < 4; m++)
#pragma unroll
                for (int n2 = 0; n2 < 4; n2++)
                    acc[m][n2] = __builtin_amdgcn_mfma_f32_16x16x32_bf16(
                        af[m], bfr[n2], acc[m][n2], 0, 0, 0);
        }
        __syncthreads();
    }
#pragma unroll
    for (int m = 0; m < 4; m++) {
        int row0 = bm * 128 + wm * 64 + m * 16 + lg * 4;
#pragma unroll
        for (int n2 = 0; n2 < 4; n2++) {
            int col = bn * 128 + wn * 64 + n2 * 16 + lr;
            float bv = bias[col];
#pragma unroll
            for (int i = 0; i < 4; i++)
                C[(size_t)(row0 + i) * N + col] = acc[m][n2][i] + bv;
        }
    }
}

// ---------------------------------------------------------------------------
// Grid-synced weight-stationary scan. 64 blocks x 512 threads; block owns
// j = bid*8..+8. Hierarchical fence-free barriers; xT loads pipelined
// across barrier 2.
// ---------------------------------------------------------------------------
__global__ __launch_bounds__(512)
void scan_sync(const unsigned short* __restrict__ xT,   // [512 t][2048 col][64 m] bf16
               const float* __restrict__ h0,            // [64 m][512 j]
               const uint2* __restrict__ warz,          // [256 kp][512 j]
               const uint* __restrict__ wan,            // [512 k][512 j]
               uint* __restrict__ hbuf,                 // [256 kp][64 m]
               uint* __restrict__ rhrxe,                // [512 k][64 m]
               uint* __restrict__ cnts,                 // barrier sets
               float* __restrict__ hseq)                // [64 m][512 t][512 j]
{
    __shared__ uint2 Wrz_l[256][JO];                    // 16 KB
    __shared__ uint  Wn_l[512][JO];                     // 16 KB
    __shared__ float part[3][8][JO][64];                // 48 KB
    __shared__ float h_loc[JO][64], z_loc[JO][64];      // 4 KB

    const int bid = blockIdx.x, tid = threadIdx.x;
    const int lane = tid & 63, wv = tid >> 6;           // 8 waves
    const int j0 = bid * JO;
    const int jF = tid >> 6, mF = tid & 63;             // finalize mapping

    uint* bar0 = cnts;
    uint* bar1 = cnts + BAR_STRIDE;

    // one-time: weights -> LDS, local h slice
    for (int i = tid; i < 256 * JO; i += 512) {
        int kp = i >> 3, j = i & 7;
        Wrz_l[kp][j] = warz[kp * 512 + j0 + j];
    }
    for (int i = tid; i < 512 * JO; i += 512) {
        int k = i >> 3, j = i & 7;
        Wn_l[k][j] = wan[k * 512 + j0 + j];
    }
    h_loc[jF][mF] = h0[mF * 512 + j0 + jF];
    __syncthreads();

    // pipelined xT gate loads for step 0
    const int jg = j0 + jF;
    const size_t xoff = (size_t)jg * 64 + mF;
    float xe = bf16_to_f32(xT[xoff]);
    float xr = bf16_to_f32(xT[xoff + (size_t)512 * 64]);
    float xz = bf16_to_f32(xT[xoff + (size_t)1024 * 64]);
    float xn = bf16_to_f32(xT[xoff + (size_t)1536 * 64]);

    for (int t = 0; t < T_; t++) {
        // ---- phase A: r,z partial dots (wave wv covers kp = wv*32..+32) ----
        {
            uint hv[32];
#pragma unroll
            for (int q = 0; q < 32; q++)
                hv[q] = ald(&hbuf[(wv * 32 + q) * 64 + lane]);
            float ar[JO] = {}, az[JO] = {};
#pragma unroll
            for (int q = 0; q < 32; q++) {
                half2_t h2 = uph2(hv[q]);
#pragma unroll
                for (int j = 0; j < JO; j++) {
                    uint2 w = *(const uint2*)&Wrz_l[wv * 32 + q][j];
                    ar[j] = fdot2(h2, uph2(w.x), ar[j]);
                    az[j] = fdot2(h2, uph2(w.y), az[j]);
                }
            }
#pragma unroll
            for (int j = 0; j < JO; j++) {
                part[0][wv][j][lane] = ar[j];
                part[1][wv][j][lane] = az[j];
            }
        }
        __syncthreads();

        // ---- finalize A (all 512 threads; coalesced rhrxe publish) ----
        {
            float sr = 0.f, sz = 0.f;
#pragma unroll
            for (int w = 0; w < 8; w++) { sr += part[0][w][jF][mF]; sz += part[1][w][jF][mF]; }
            float r = sigmoidf_(xr + sr);
            float z = sigmoidf_(xz + sz);
            float h = h_loc[jF][mF];
            z_loc[jF][mF] = z;
            ast(&rhrxe[jg * 64 + mF], pkh2(r * h, r * xe));
        }
        // ---- barrier 1: all rhrxe published ----
        gbar2(bar0, (uint)t, tid, bid);

        // ---- phase B: n partial dots (wave wv covers k = wv*64..+64) ----
        {
            float an[JO] = {};
#pragma unroll
            for (int ch = 0; ch < 2; ch++) {
                uint rv[32];
#pragma unroll
                for (int q = 0; q < 32; q++)
                    rv[q] = ald(&rhrxe[(wv * 64 + ch * 32 + q) * 64 + lane]);
#pragma unroll
                for (int q = 0; q < 32; q++) {
                    half2_t p2 = uph2(rv[q]);
#pragma unroll
                    for (int j = 0; j < JO; j++)
                        an[j] = fdot2(p2, uph2(Wn_l[wv * 64 + ch * 32 + q][j]), an[j]);
                }
            }
#pragma unroll
            for (int j = 0; j < JO; j++) part[2][wv][j][lane] = an[j];
        }
        __syncthreads();

        // ---- finalize B: tanh, h update ----
        {
            float sn = 0.f;
#pragma unroll
            for (int w = 0; w < 8; w++) sn += part[2][w][jF][mF];
            float nn = tanhf(xn + sn);
            float z = z_loc[jF][mF];
            float h = h_loc[jF][mF];
            h_loc[jF][mF] = (1.f - z) * h + z * nn;
        }
        __syncthreads();

        // ---- publish new h (f16 pairs) + write hseq (32B bursts) ----
        if (tid < (JO / 2) * 64) {
            int jp = tid >> 6, mh = tid & 63;
            ast(&hbuf[(bid * (JO / 2) + jp) * 64 + mh],
                pkh2(h_loc[2 * jp][mh], h_loc[2 * jp + 1][mh]));
        }
        {
            int js = tid & 7, ms = tid >> 3;
            hseq[((size_t)ms * 512 + t) * 512 + j0 + js] = h_loc[js][ms];
        }

        // ---- prefetch next step's xT gates (in flight across barrier 2) ----
        float xe2 = 0.f, xr2 = 0.f, xz2 = 0.f, xn2 = 0.f;
        if (t + 1 < T_) {
            const size_t xb = (size_t)(t + 1) * 2048 * 64 + xoff;
            xe2 = bf16_to_f32(xT[xb]);
            xr2 = bf16_to_f32(xT[xb + (size_t)512 * 64]);
            xz2 = bf16_to_f32(xT[xb + (size_t)1024 * 64]);
            xn2 = bf16_to_f32(xT[xb + (size_t)1536 * 64]);
        }
        // ---- barrier 2: all h published ----
        gbar2(bar1, (uint)t, tid, bid);
        xe = xe2; xr = xr2; xz = xz2; xn = xn2;
    }
}

// ---------------------------------------------------------------------------
extern "C" void kernel_launch(void* const* d_in, const int* in_sizes, int n_in,
                              void* d_out, int out_size, void* d_ws, size_t ws_size,
                              hipStream_t stream) {
    const float* x    = (const float*)d_in[0];
    const float* h0   = (const float*)d_in[1];
    const float* We2h = (const float*)d_in[2];
    const float* Wrx  = (const float*)d_in[3];
    const float* Wrh  = (const float*)d_in[4];
    const float* Wre  = (const float*)d_in[5];
    const float* br   = (const float*)d_in[6];
    const float* Wzx  = (const float*)d_in[7];
    const float* Wzh  = (const float*)d_in[8];
    const float* Wze  = (const float*)d_in[9];
    const float* bz   = (const float*)d_in[10];
    const float* Wnx  = (const float*)d_in[11];
    const float* Wnh  = (const float*)d_in[12];
    const float* Wne  = (const float*)d_in[13];
    const float* bn   = (const float*)d_in[14];
    const float* Wo   = (const float*)d_in[15];
    const float* bo   = (const float*)d_in[16];

    // workspace layout (bytes)
    char* w = (char*)d_ws;
    unsigned short* xT    = (unsigned short*)(w);                  // 134217728
    uint2*          warz  = (uint2*)(w + 134217728);               // 1048576
    uint*           wan   = (uint*)(w + 135266304);                // 1048576
    unsigned short* WcatT = (unsigned short*)(w + 136314880);      // 1048576
    unsigned short* WoT   = (unsigned short*)(w + 137363456);      // 262144
    float*          biascat = (float*)(w + 137625600);             // 8192
    float*          Pr    = (float*)(w + 137633792);               // 524288
    float*          Pz    = (float*)(w + 138158080);               // 524288
    uint*           hbuf  = (uint*)(w + 138682368);                // 65536
    uint*           rhrxe = (uint*)(w + 138747904);                // 131072
    uint*           cnts  = (uint*)(w + 138878976);                // 16384 (2 barrier sets)

    float* out  = (float*)d_out;                    // [B,T,D]
    float* hseq = (float*)d_out + (size_t)M_ * D_;  // [B,T,H]

    hipMemsetAsync(cnts, 0, 2 * BAR_STRIDE * sizeof(uint), stream);

    // 1. composite input weights + packed scan weights
    comp_p<<<(256 * 512 + 255) / 256, 256, 0, stream>>>(We2h, Wre, Wze, Pr, Pz);
    build_wt<<<(2048 * 256 + 256 * 512 + 255) / 256, 256, 0, stream>>>(
        We2h, Wrx, Wzx, Wnx, Pr, Pz, br, bz, bn, Wo, WcatT, biascat, WoT);
    build_wscan<<<(256 * 512 + 512 * 512 + 255) / 256, 256, 0, stream>>>(
        Wrh, Wre, Wzh, Wze, Wnh, Wne, warz, wan);
    init_hbuf<<<(256 * 64 + 255) / 256, 256, 0, stream>>>(h0, hbuf);

    // 2. pre-projections directly into xT[t][col][m]
    {
        dim3 grid(T_ / 2, 2048 / 128);
        gemmx_kernel<<<grid, 256, 0, stream>>>(x, WcatT, biascat, xT);
    }
    // 3. grid-synced scan -> hseq
    scan_sync<<<NBLK, 512, 0, stream>>>(xT, h0, warz, wan, hbuf, rhrxe, cnts, hseq);
    // 4. readout: [32768,512] @ [512,256] + bo -> out
    {
        dim3 grid(M_ / 128, D_ / 128);
        gemm_out_kernel<<<grid, 256, 0, stream>>>(hseq, WoT, bo, out, M_, D_, H_);
    }
}

// Round 8
// 5559.661 us; speedup vs baseline: 2.6665x; 1.0234x over previous
//
#include <hip/hip_runtime.h>
#include <hip/hip_bf16.h>
#include <hip/hip_fp16.h>

// Problem constants
#define B_ 64
#define T_ 512
#define D_ 256
#define H_ 512
#define M_ (B_*T_)          // 32768

#define NBLK 64             // scan blocks
#define JO 8                // hidden columns owned per scan block

typedef unsigned int uint;
typedef __attribute__((ext_vector_type(8))) short bf16x8;
typedef __attribute__((ext_vector_type(4))) float f32x4;
typedef _Float16 half_t;
typedef __attribute__((ext_vector_type(2))) _Float16 half2_t;

__device__ __forceinline__ unsigned short f32_to_bf16(float f) {
    unsigned u = __builtin_bit_cast(unsigned, f);
    unsigned r = (u + 0x7fffu + ((u >> 16) & 1u)) >> 16;
    return (unsigned short)r;
}
__device__ __forceinline__ float bf16_to_f32(unsigned short h) {
    unsigned u = ((unsigned)h) << 16;
    return __builtin_bit_cast(float, u);
}
__device__ __forceinline__ unsigned pkh2(float a, float b) {
    half2_t h; h.x = (half_t)a; h.y = (half_t)b;
    return __builtin_bit_cast(unsigned, h);
}
__device__ __forceinline__ half2_t uph2(unsigned u) {
    return __builtin_bit_cast(half2_t, u);
}

#if __has_builtin(__builtin_amdgcn_fdot2)
__device__ __forceinline__ float fdot2(half2_t a, half2_t b, float c) {
    return __builtin_amdgcn_fdot2(a, b, c, false);
}
#else
__device__ __forceinline__ float fdot2(half2_t a, half2_t b, float c) {
    return c + (float)a.x * (float)b.x + (float)a.y * (float)b.y;
}
#endif

// agent-scope (cross-XCD coherent, L2-bypassing) relaxed atomics
__device__ __forceinline__ uint ald(const uint* p) {
    return __hip_atomic_load(p, __ATOMIC_RELAXED, __HIP_MEMORY_SCOPE_AGENT);
}
__device__ __forceinline__ void ast(uint* p, uint v) {
    __hip_atomic_store(p, v, __ATOMIC_RELAXED, __HIP_MEMORY_SCOPE_AGENT);
}

__device__ __forceinline__ float sigmoidf_(float x) {
    return 1.f / (1.f + __expf(-x));
}

// Single-hop flag-array grid barrier.
//  arrival: block bid stores monotonic `target` into flags[bid*4] (no RMW).
//  detect:  wave 0 of EVERY block polls all 64 flags (lane l -> flags[l*4])
//           and exits when __all(f >= target). One L3 hop total.
//  entry __syncthreads drains this block's publish stores (vmcnt(0) before
//  s_barrier); exit is a RAW s_barrier so other waves' in-flight loads
//  (prefetch) survive. All cross-block data moves via agent-scope atomics
//  (L2-bypassing), so no cache fences are needed.
__device__ __forceinline__ void gbar(uint* flags, uint target, int tid, int bid) {
    __syncthreads();                      // drain publishes; all waves synced
    if (tid < 64) {                       // wave 0
        if (tid == 0)
            __hip_atomic_store(&flags[bid * 4], target,
                               __ATOMIC_RELAXED, __HIP_MEMORY_SCOPE_AGENT);
        int it = 0;
        uint f;
        do {
            f = __hip_atomic_load(&flags[tid * 4],
                                  __ATOMIC_RELAXED, __HIP_MEMORY_SCOPE_AGENT);
            if (++it > (1 << 24)) break;  // bounded: fail loud, not hang
        } while (!__all(f >= target));
    }
    __builtin_amdgcn_s_barrier();         // raw: no vmcnt drain on exit
}

// ---------------------------------------------------------------------------
// P = We2h @ W  for r and z gates
// ---------------------------------------------------------------------------
__global__ void comp_p(const float* __restrict__ We2h, const float* __restrict__ Wre,
                       const float* __restrict__ Wze,
                       float* __restrict__ Pr, float* __restrict__ Pz) {
    int tid = blockIdx.x * blockDim.x + threadIdx.x;   // 256*512
    if (tid >= 256 * 512) return;
    int k = tid >> 9, j = tid & 511;
    float ar = 0.f, az = 0.f;
    for (int kk = 0; kk < 512; kk++) {
        float e = We2h[k * 512 + kk];
        ar += e * Wre[kk * 512 + j];
        az += e * Wze[kk * 512 + j];
    }
    Pr[tid] = ar;
    Pz[tid] = az;
}

// ---------------------------------------------------------------------------
// Build bf16 weights for the big GEMMs.
// ---------------------------------------------------------------------------
__global__ void build_wt(const float* __restrict__ We2h, const float* __restrict__ Wrx,
                         const float* __restrict__ Wzx, const float* __restrict__ Wnx,
                         const float* __restrict__ Pr, const float* __restrict__ Pz,
                         const float* __restrict__ br, const float* __restrict__ bz,
                         const float* __restrict__ bn, const float* __restrict__ Wo,
                         unsigned short* __restrict__ WcatT, float* __restrict__ biascat,
                         unsigned short* __restrict__ WoT) {
    int tid = blockIdx.x * blockDim.x + threadIdx.x;
    const int total1 = 2048 * 256;
    if (tid < total1) {
        int n = tid >> 8, k = tid & 255;
        int sel = n >> 9, nl = n & 511;
        float v;
        if (sel == 0)      v = We2h[k * 512 + nl];
        else if (sel == 1) v = Wrx[k * 512 + nl] + Pr[k * 512 + nl];
        else if (sel == 2) v = Wzx[k * 512 + nl] + Pz[k * 512 + nl];
        else               v = Wnx[k * 512 + nl];
        WcatT[tid] = f32_to_bf16(v);
        if (k == 0) {
            float bv = sel == 0 ? 0.f : sel == 1 ? br[nl] : sel == 2 ? bz[nl] : bn[nl];
            biascat[n] = bv;
        }
    } else {
        int t2 = tid - total1;
        if (t2 < 256 * 512) {
            int n = t2 >> 9, k = t2 & 511;
            WoT[t2] = f32_to_bf16(Wo[k * 256 + n]);
        }
    }
}

// ---------------------------------------------------------------------------
// Packed f16 recurrent weights (transformed):
//  warz uint2 [256 kp][512 j]: {pkh2(Ar[2kp],Ar[2kp+1]), pkh2(Az...)}, A=Wh-We
//  wan  uint  [512 k][512 j]:  pkh2(An[k][j], Wne[k][j]),  An = Wnh - Wne
// ---------------------------------------------------------------------------
__global__ void build_wscan(const float* __restrict__ Wrh, const float* __restrict__ Wre,
                            const float* __restrict__ Wzh, const float* __restrict__ Wze,
                            const float* __restrict__ Wnh, const float* __restrict__ Wne,
                            uint2* __restrict__ warz, uint* __restrict__ wan) {
    int tid = blockIdx.x * blockDim.x + threadIdx.x;
    if (tid < 256 * 512) {
        int kp = tid >> 9, j = tid & 511;
        int k0 = 2 * kp;
        float ar0 = Wrh[k0 * 512 + j] - Wre[k0 * 512 + j];
        float ar1 = Wrh[(k0 + 1) * 512 + j] - Wre[(k0 + 1) * 512 + j];
        float az0 = Wzh[k0 * 512 + j] - Wze[k0 * 512 + j];
        float az1 = Wzh[(k0 + 1) * 512 + j] - Wze[(k0 + 1) * 512 + j];
        warz[tid] = make_uint2(pkh2(ar0, ar1), pkh2(az0, az1));
    }
    int t2 = tid - 256 * 512;
    if (t2 >= 0 && t2 < 512 * 512) {
        int k = t2 >> 9, j = t2 & 511;
        float an = Wnh[k * 512 + j] - Wne[k * 512 + j];
        wan[t2] = pkh2(an, Wne[k * 512 + j]);
    }
}

// ---------------------------------------------------------------------------
// init hbuf: [256 kp][64 m] uint = (f16 h[m][2kp], f16 h[m][2kp+1])
// ---------------------------------------------------------------------------
__global__ void init_hbuf(const float* __restrict__ h0, uint* __restrict__ hbuf) {
    int tid = blockIdx.x * blockDim.x + threadIdx.x;   // 256*64
    if (tid >= 256 * 64) return;
    int kp = tid >> 6, m = tid & 63;
    hbuf[tid] = pkh2(h0[m * 512 + 2 * kp], h0[m * 512 + 2 * kp + 1]);
}

// ---------------------------------------------------------------------------
// GEMM-X: writes xproj directly in scan layout xT[t][col][m] bf16.
// ---------------------------------------------------------------------------
__global__ __launch_bounds__(256)
void gemmx_kernel(const float* __restrict__ A, const unsigned short* __restrict__ BT,
                  const float* __restrict__ bias, unsigned short* __restrict__ xT) {
    __shared__ unsigned short Asm[128 * 64];
    __shared__ unsigned short Bsm[128 * 64];
    __shared__ unsigned short Csm[128][128];   // [col][row]
    const int tid = threadIdx.x;
    const int t0 = blockIdx.x * 2;        // time-pair
    const int c0 = blockIdx.y * 128;      // col tile
    const int lane = tid & 63, wid = tid >> 6;
    const int wm = wid >> 1, wn = wid & 1;
    const int lr = lane & 15, lg = lane >> 4;

    f32x4 acc[4][4] = {};

    const int srow = tid >> 1, shalf = tid & 1;
    const int rowA = (srow & 63) * 512 + t0 + (srow >> 6);     // (b,t) -> A row
    const float* Arow = A + (size_t)rowA * 256 + shalf * 32;
    const unsigned short* Brow = BT + (size_t)(c0 + srow) * 256 + shalf * 32;
    unsigned short* As = &Asm[srow * 64 + shalf * 32];
    unsigned short* Bs = &Bsm[srow * 64 + shalf * 32];

    for (int kt = 0; kt < 256; kt += 64) {
#pragma unroll
        for (int q = 0; q < 8; q++) {
            float4 v = *(const float4*)(Arow + kt + q * 4);
            unsigned p0 = ((unsigned)f32_to_bf16(v.y) << 16) | f32_to_bf16(v.x);
            unsigned p1 = ((unsigned)f32_to_bf16(v.w) << 16) | f32_to_bf16(v.z);
            *(uint2*)(As + q * 4) = make_uint2(p0, p1);
        }
#pragma unroll
        for (int q = 0; q < 4; q++) {
            uint4 v = *(const uint4*)(Brow + kt + q * 8);
            *(uint4*)(Bs + q * 8) = v;
        }
        __syncthreads();
#pragma unroll
        for (int ks = 0; ks < 2; ks++) {
            bf16x8 af[4], bfr[4];
#pragma unroll
            for (int m = 0; m < 4; m++)
                af[m] = *(const bf16x8*)&Asm[(wm * 64 + m * 16 + lr) * 64 + ks * 32 + lg * 8];
#pragma unroll
            for (int n2 = 0; n2 < 4; n2++)
                bfr[n2] = *(const bf16x8*)&Bsm[(wn * 64 + n2 * 16 + lr) * 64 + ks * 32 + lg * 8];
#pragma unroll
            for (int m = 0; m < 4; m++)
#pragma unroll
                for (int n2 = 0; n2 < 4; n2++)
                    acc[m][n2] = __builtin_amdgcn_mfma_f32_16x16x32_bf16(
                        af[m], bfr[n2], acc[m][n2], 0, 0, 0);
        }
        __syncthreads();
    }
#pragma unroll
    for (int m = 0; m < 4; m++) {
        int r0 = wm * 64 + m * 16 + lg * 4;
#pragma unroll
        for (int n2 = 0; n2 < 4; n2++) {
            int c = wn * 64 + n2 * 16 + lr;
            float bv = bias[c0 + c];
#pragma unroll
            for (int i = 0; i < 4; i++)
                Csm[c][r0 + i] = f32_to_bf16(acc[m][n2][i] + bv);
        }
    }
    __syncthreads();
#pragma unroll
    for (int th = 0; th < 2; th++) {
        uint4* dst = (uint4*)(xT + ((size_t)(t0 + th) * 2048 + c0) * 64);
        for (int q = tid; q < 1024; q += 256) {
            int c = q >> 3, b0 = (q & 7) * 8;
            dst[q] = *(const uint4*)&Csm[c][th * 64 + b0];
        }
        __syncthreads();
    }
}

// ---------------------------------------------------------------------------
// Readout GEMM: A fp32 [M][K], BT bf16 [N][K], C fp32 + bias.
// ---------------------------------------------------------------------------
__global__ __launch_bounds__(256)
void gemm_out_kernel(const float* __restrict__ A, const unsigned short* __restrict__ BT,
                     const float* __restrict__ bias, float* __restrict__ C,
                     int M, int N, int K) {
    __shared__ unsigned short Asm[128 * 64];
    __shared__ unsigned short Bsm[128 * 64];
    const int tid = threadIdx.x;
    const int bm = blockIdx.x, bn = blockIdx.y;
    const int lane = tid & 63, wid = tid >> 6;
    const int wm = wid >> 1, wn = wid & 1;
    const int lr = lane & 15, lg = lane >> 4;

    f32x4 acc[4][4] = {};

    const int srow = tid >> 1, shalf = tid & 1;
    const float* Arow = A + (size_t)(bm * 128 + srow) * K + shalf * 32;
    const unsigned short* Brow = BT + (size_t)(bn * 128 + srow) * K + shalf * 32;
    unsigned short* As = &Asm[srow * 64 + shalf * 32];
    unsigned short* Bs = &Bsm[srow * 64 + shalf * 32];

    for (int kt = 0; kt < K; kt += 64) {
#pragma unroll
        for (int q = 0; q < 8; q++) {
            float4 v = *(const float4*)(Arow + kt + q * 4);
            unsigned p0 = ((unsigned)f32_to_bf16(v.y) << 16) | f32_to_bf16(v.x);
            unsigned p1 = ((unsigned)f32_to_bf16(v.w) << 16) | f32_to_bf16(v.z);
            *(uint2*)(As + q * 4) = make_uint2(p0, p1);
        }
#pragma unroll
        for (int q = 0; q < 4; q++) {
            uint4 v = *(const uint4*)(Brow + kt + q * 8);
            *(uint4*)(Bs + q * 8) = v;
        }
        __syncthreads();
#pragma unroll
        for (int ks = 0; ks < 2; ks++) {
            bf16x8 af[4], bfr[4];
#pragma unroll
            for (int m = 0; m < 4; m++)
                af[m] = *(const bf16x8*)&Asm[(wm * 64 + m * 16 + lr) * 64 + ks * 32 + lg * 8];
#pragma unroll
            for (int n2 = 0; n2 < 4; n2++)
                bfr[n2] = *(const bf16x8*)&Bsm[(wn * 64 + n2 * 16 + lr) * 64 + ks * 32 + lg * 8];
#pragma unroll
            for (int m = 0; m < 4; m++)
#pragma unroll
                for (int n2 = 0; n2 < 4; n2++)
                    acc[m][n2] = __builtin_amdgcn_mfma_f32_16x16x32_bf16(
                        af[m], bfr[n2], acc[m][n2], 0, 0, 0);
        }
        __syncthreads();
    }
#pragma unroll
    for (int m = 0; m < 4; m++) {
        int row0 = bm * 128 + wm * 64 + m * 16 + lg * 4;
#pragma unroll
        for (int n2 = 0; n2 < 4; n2++) {
            int col = bn * 128 + wn * 64 + n2 * 16 + lr;
            float bv = bias[col];
#pragma unroll
            for (int i = 0; i < 4; i++)
                C[(size_t)(row0 + i) * N + col] = acc[m][n2][i] + bv;
        }
    }
}

// ---------------------------------------------------------------------------
// Grid-synced weight-stationary scan. 64 blocks x 512 threads; block owns
// j = bid*8..+8. Single-hop flag-array barriers; xT prefetch issued inside
// barrier 2 (after entry-sync) so it survives the raw exit s_barrier.
// ---------------------------------------------------------------------------
__global__ __launch_bounds__(512)
void scan_sync(const unsigned short* __restrict__ xT,   // [512 t][2048 col][64 m] bf16
               const float* __restrict__ h0,            // [64 m][512 j]
               const uint2* __restrict__ warz,          // [256 kp][512 j]
               const uint* __restrict__ wan,            // [512 k][512 j]
               uint* __restrict__ hbuf,                 // [256 kp][64 m]
               uint* __restrict__ rhrxe,                // [512 k][64 m]
               uint* __restrict__ flags,                // [NBLK*4]
               float* __restrict__ hseq)                // [64 m][512 t][512 j]
{
    __shared__ uint2 Wrz_l[256][JO];                    // 16 KB
    __shared__ uint  Wn_l[512][JO];                     // 16 KB
    __shared__ float part[3][8][JO][64];                // 48 KB
    __shared__ float h_loc[JO][64], z_loc[JO][64];      // 4 KB

    const int bid = blockIdx.x, tid = threadIdx.x;
    const int lane = tid & 63, wv = tid >> 6;           // 8 waves
    const int j0 = bid * JO;
    const int jF = tid >> 6, mF = tid & 63;             // finalize mapping

    // one-time: weights -> LDS, local h slice
    for (int i = tid; i < 256 * JO; i += 512) {
        int kp = i >> 3, j = i & 7;
        Wrz_l[kp][j] = warz[kp * 512 + j0 + j];
    }
    for (int i = tid; i < 512 * JO; i += 512) {
        int k = i >> 3, j = i & 7;
        Wn_l[k][j] = wan[k * 512 + j0 + j];
    }
    h_loc[jF][mF] = h0[mF * 512 + j0 + jF];
    __syncthreads();

    // xT gate loads for step 0 (raw ushorts; convert at use)
    const int jg = j0 + jF;
    const size_t xoff = (size_t)jg * 64 + mF;
    unsigned short pxe = xT[xoff];
    unsigned short pxr = xT[xoff + (size_t)512 * 64];
    unsigned short pxz = xT[xoff + (size_t)1024 * 64];
    unsigned short pxn = xT[xoff + (size_t)1536 * 64];

    for (int t = 0; t < T_; t++) {
        // ---- phase A: r,z partial dots (wave wv covers kp = wv*32..+32) ----
        {
            uint hv[32];
#pragma unroll
            for (int q = 0; q < 32; q++)
                hv[q] = ald(&hbuf[(wv * 32 + q) * 64 + lane]);
            float ar[JO] = {}, az[JO] = {};
#pragma unroll
            for (int q = 0; q < 32; q++) {
                half2_t h2 = uph2(hv[q]);
#pragma unroll
                for (int j = 0; j < JO; j++) {
                    uint2 w = *(const uint2*)&Wrz_l[wv * 32 + q][j];
                    ar[j] = fdot2(h2, uph2(w.x), ar[j]);
                    az[j] = fdot2(h2, uph2(w.y), az[j]);
                }
            }
#pragma unroll
            for (int j = 0; j < JO; j++) {
                part[0][wv][j][lane] = ar[j];
                part[1][wv][j][lane] = az[j];
            }
        }
        __syncthreads();

        // ---- finalize A (all 512 threads; coalesced rhrxe publish) ----
        float xe = bf16_to_f32(pxe), xn_f = bf16_to_f32(pxn);
        {
            float sr = 0.f, sz = 0.f;
#pragma unroll
            for (int w = 0; w < 8; w++) { sr += part[0][w][jF][mF]; sz += part[1][w][jF][mF]; }
            float r = sigmoidf_(bf16_to_f32(pxr) + sr);
            float z = sigmoidf_(bf16_to_f32(pxz) + sz);
            float h = h_loc[jF][mF];
            z_loc[jF][mF] = z;
            ast(&rhrxe[jg * 64 + mF], pkh2(r * h, r * xe));
        }
        // ---- barrier 1: all rhrxe published ----
        gbar(flags, 2u * (uint)t + 1u, tid, bid);

        // ---- phase B: n partial dots (wave wv covers k = wv*64..+64) ----
        {
            float an[JO] = {};
#pragma unroll
            for (int ch = 0; ch < 2; ch++) {
                uint rv[32];
#pragma unroll
                for (int q = 0; q < 32; q++)
                    rv[q] = ald(&rhrxe[(wv * 64 + ch * 32 + q) * 64 + lane]);
#pragma unroll
                for (int q = 0; q < 32; q++) {
                    half2_t p2 = uph2(rv[q]);
#pragma unroll
                    for (int j = 0; j < JO; j++)
                        an[j] = fdot2(p2, uph2(Wn_l[wv * 64 + ch * 32 + q][j]), an[j]);
                }
            }
#pragma unroll
            for (int j = 0; j < JO; j++) part[2][wv][j][lane] = an[j];
        }
        __syncthreads();

        // ---- finalize B: tanh, h update ----
        {
            float sn = 0.f;
#pragma unroll
            for (int w = 0; w < 8; w++) sn += part[2][w][jF][mF];
            float nn = tanhf(xn_f + sn);
            float z = z_loc[jF][mF];
            float h = h_loc[jF][mF];
            h_loc[jF][mF] = (1.f - z) * h + z * nn;
        }
        __syncthreads();

        // ---- publish new h (f16 pairs) + write hseq (32B bursts) ----
        if (tid < (JO / 2) * 64) {
            int jp = tid >> 6, mh = tid & 63;
            ast(&hbuf[(bid * (JO / 2) + jp) * 64 + mh],
                pkh2(h_loc[2 * jp][mh], h_loc[2 * jp + 1][mh]));
        }
        {
            int js = tid & 7, ms = tid >> 3;
            hseq[((size_t)ms * 512 + t) * 512 + j0 + js] = h_loc[js][ms];
        }

        // ---- barrier 2 (inlined): entry-sync drains publishes, THEN issue
        //      next-step xT prefetch (survives the raw exit s_barrier) ----
        __syncthreads();
        if (t + 1 < T_) {
            const size_t xb = (size_t)(t + 1) * 2048 * 64 + xoff;
            pxe = xT[xb];
            pxr = xT[xb + (size_t)512 * 64];
            pxz = xT[xb + (size_t)1024 * 64];
            pxn = xT[xb + (size_t)1536 * 64];
        }
        __builtin_amdgcn_sched_barrier(0);   // pin prefetch issue here
        if (tid < 64) {
            if (tid == 0)
                __hip_atomic_store(&flags[bid * 4], 2u * (uint)t + 2u,
                                   __ATOMIC_RELAXED, __HIP_MEMORY_SCOPE_AGENT);
            int it = 0;
            uint f;
            do {
                f = __hip_atomic_load(&flags[tid * 4],
                                      __ATOMIC_RELAXED, __HIP_MEMORY_SCOPE_AGENT);
                if (++it > (1 << 24)) break;
            } while (!__all(f >= 2u * (uint)t + 2u));
        }
        __builtin_amdgcn_s_barrier();
    }
}

// ---------------------------------------------------------------------------
extern "C" void kernel_launch(void* const* d_in, const int* in_sizes, int n_in,
                              void* d_out, int out_size, void* d_ws, size_t ws_size,
                              hipStream_t stream) {
    const float* x    = (const float*)d_in[0];
    const float* h0   = (const float*)d_in[1];
    const float* We2h = (const float*)d_in[2];
    const float* Wrx  = (const float*)d_in[3];
    const float* Wrh  = (const float*)d_in[4];
    const float* Wre  = (const float*)d_in[5];
    const float* br   = (const float*)d_in[6];
    const float* Wzx  = (const float*)d_in[7];
    const float* Wzh  = (const float*)d_in[8];
    const float* Wze  = (const float*)d_in[9];
    const float* bz   = (const float*)d_in[10];
    const float* Wnx  = (const float*)d_in[11];
    const float* Wnh  = (const float*)d_in[12];
    const float* Wne  = (const float*)d_in[13];
    const float* bn   = (const float*)d_in[14];
    const float* Wo   = (const float*)d_in[15];
    const float* bo   = (const float*)d_in[16];

    // workspace layout (bytes)
    char* w = (char*)d_ws;
    unsigned short* xT    = (unsigned short*)(w);                  // 134217728
    uint2*          warz  = (uint2*)(w + 134217728);               // 1048576
    uint*           wan   = (uint*)(w + 135266304);                // 1048576
    unsigned short* WcatT = (unsigned short*)(w + 136314880);      // 1048576
    unsigned short* WoT   = (unsigned short*)(w + 137363456);      // 262144
    float*          biascat = (float*)(w + 137625600);             // 8192
    float*          Pr    = (float*)(w + 137633792);               // 524288
    float*          Pz    = (float*)(w + 138158080);               // 524288
    uint*           hbuf  = (uint*)(w + 138682368);                // 65536
    uint*           rhrxe = (uint*)(w + 138747904);                // 131072
    uint*           flags = (uint*)(w + 138878976);                // 1024

    float* out  = (float*)d_out;                    // [B,T,D]
    float* hseq = (float*)d_out + (size_t)M_ * D_;  // [B,T,H]

    hipMemsetAsync(flags, 0, NBLK * 4 * sizeof(uint), stream);

    // 1. composite input weights + packed scan weights
    comp_p<<<(256 * 512 + 255) / 256, 256, 0, stream>>>(We2h, Wre, Wze, Pr, Pz);
    build_wt<<<(2048 * 256 + 256 * 512 + 255) / 256, 256, 0, stream>>>(
        We2h, Wrx, Wzx, Wnx, Pr, Pz, br, bz, bn, Wo, WcatT, biascat, WoT);
    build_wscan<<<(256 * 512 + 512 * 512 + 255) / 256, 256, 0, stream>>>(
        Wrh, Wre, Wzh, Wze, Wnh, Wne, warz, wan);
    init_hbuf<<<(256 * 64 + 255) / 256, 256, 0, stream>>>(h0, hbuf);

    // 2. pre-projections directly into xT[t][col][m]
    {
        dim3 grid(T_ / 2, 2048 / 128);
        gemmx_kernel<<<grid, 256, 0, stream>>>(x, WcatT, biascat, xT);
    }
    // 3. grid-synced scan -> hseq
    scan_sync<<<NBLK, 512, 0, stream>>>(xT, h0, warz, wan, hbuf, rhrxe, flags, hseq);
    // 4. readout: [32768,512] @ [512,256] + bo -> out
    {
        dim3 grid(M_ / 128, D_ / 128);
        gemm_out_kernel<<<grid, 256, 0, stream>>>(hseq, WoT, bo, out, M_, D_, H_);
    }
}